// Round 1
// baseline (764.193 us; speedup 1.0000x reference)
//
#include <hip/hip_runtime.h>
#include <math.h>

// Problem constants (hard-coded from reference)
// B=2, N=1024, C=256, HEADS=8, DH=32, INNER=256, L=3, P=9, FF=512, DEPTH=2
// LEN = 128*128 + 64*64 + 32*32 = 21504, level starts {0, 16384, 20480}

#define DEV __device__ __forceinline__

DEV float gelu_f(float v) { return 0.5f * v * (1.0f + erff(v * 0.7071067811865475f)); }

// ---------------------------------------------------------------- copy x -> out
__global__ __launch_bounds__(256) void k_copy(const float4* __restrict__ a, float4* __restrict__ o, int n4) {
    int i = blockIdx.x * 256 + threadIdx.x;
    if (i < n4) o[i] = a[i];
}

// ------------------------------------------------- row stats (mean, rstd) of src
// one wave per 256-float row; 4 rows per block
__global__ __launch_bounds__(256) void k_rowstats(const float* __restrict__ x, float* __restrict__ st) {
    int wid = threadIdx.x >> 6, lane = threadIdx.x & 63;
    size_t row = (size_t)blockIdx.x * 4 + wid;
    float4 v = ((const float4*)(x + row * 256))[lane];
    float s = (v.x + v.y) + (v.z + v.w);
#pragma unroll
    for (int o = 32; o; o >>= 1) s += __shfl_xor(s, o);
    float mean = s * (1.0f / 256.0f);
    float dx = v.x - mean, dy = v.y - mean, dz = v.z - mean, dw = v.w - mean;
    float q = (dx * dx + dy * dy) + (dz * dz + dw * dw);
#pragma unroll
    for (int o = 32; o; o >>= 1) q += __shfl_xor(q, o);
    if (lane == 0) {
        st[row * 2] = mean;
        st[row * 2 + 1] = 1.0f / sqrtf(q * (1.0f / 256.0f) + 1e-5f);
    }
}

// ---------------------------------------------------------------- cpe
__global__ __launch_bounds__(256) void k_cpe(const float* __restrict__ cpos, const float* __restrict__ Wp,
                                             const float* __restrict__ bp, float* __restrict__ cpe) {
    int bn = blockIdx.x, c = threadIdx.x;
    float px = cpos[(size_t)bn * 6 + 0], py = cpos[(size_t)bn * 6 + 1];  // level-0 ref point
    cpe[(size_t)bn * 256 + c] = px * Wp[c] + py * Wp[256 + c] + bp[c];
}

// ------------------------------------------- out = LN(x [+pre]) * g + b [+post]
// one wave per row, 4 rows/block, rows = 2048
__global__ __launch_bounds__(256) void k_lnfused(const float* __restrict__ x, const float* pre, const float* post,
                                                 const float* __restrict__ g, const float* __restrict__ b,
                                                 float* __restrict__ out) {
    int wid = threadIdx.x >> 6, lane = threadIdx.x & 63;
    size_t row = (size_t)blockIdx.x * 4 + wid;
    float4 v = ((const float4*)(x + row * 256))[lane];
    if (pre) {
        float4 p = ((const float4*)(pre + row * 256))[lane];
        v.x += p.x; v.y += p.y; v.z += p.z; v.w += p.w;
    }
    float s = (v.x + v.y) + (v.z + v.w);
#pragma unroll
    for (int o = 32; o; o >>= 1) s += __shfl_xor(s, o);
    float mean = s * (1.0f / 256.0f);
    float dx = v.x - mean, dy = v.y - mean, dz = v.z - mean, dw = v.w - mean;
    float q = (dx * dx + dy * dy) + (dz * dz + dw * dw);
#pragma unroll
    for (int o = 32; o; o >>= 1) q += __shfl_xor(q, o);
    float rstd = 1.0f / sqrtf(q * (1.0f / 256.0f) + 1e-5f);
    float4 gg = ((const float4*)g)[lane], bb = ((const float4*)b)[lane];
    float4 o4;
    o4.x = dx * rstd * gg.x + bb.x;
    o4.y = dy * rstd * gg.y + bb.y;
    o4.z = dz * rstd * gg.z + bb.z;
    o4.w = dw * rstd * gg.w + bb.w;
    if (post) {
        float4 p = ((const float4*)(post + row * 256))[lane];
        o4.x += p.x; o4.y += p.y; o4.z += p.z; o4.w += p.w;
    }
    ((float4*)(out + row * 256))[lane] = o4;
}

// ---------------------------------------------------------------- KNN top-k
// one wave per query; 4 queries/block; pos3d[b] staged in LDS.
// replicates jax: d2 = sq[n]+sq[m]-2*dot ; stable (value,index) k-smallest.
template <int KK>
__global__ __launch_bounds__(256) void k_knn(const float* __restrict__ pos, int* __restrict__ kidx) {
    __shared__ float sp[3072];
    int b = blockIdx.x >> 8;
    int n0 = (blockIdx.x & 255) * 4;
    for (int t = threadIdx.x; t < 3072; t += 256) sp[t] = pos[(size_t)b * 3072 + t];
    __syncthreads();
    int wid = threadIdx.x >> 6, lane = threadIdx.x & 63;
    int n = n0 + wid;
    float qx = sp[n * 3], qy = sp[n * 3 + 1], qz = sp[n * 3 + 2];
    float sqn = (qx * qx + qy * qy) + qz * qz;
    unsigned long long key[16];
#pragma unroll
    for (int t = 0; t < 16; t++) {
        int m = t * 64 + lane;
        float mx = sp[m * 3], my = sp[m * 3 + 1], mz = sp[m * 3 + 2];
        float sqm = (mx * mx + my * my) + mz * mz;
        float dt = (qx * mx + qy * my) + qz * mz;
        float d2 = (sqn + sqm) - 2.0f * dt;
        unsigned u = __float_as_uint(d2);
        u = (u & 0x80000000u) ? ~u : (u | 0x80000000u);  // order-preserving float->uint
        key[t] = ((unsigned long long)u << 32) | (unsigned)m;
    }
    int* out = kidx + ((size_t)b * 1024 + n) * KK;
    for (int sel = 0; sel < KK; sel++) {
        unsigned long long mk = key[0];
#pragma unroll
        for (int t = 1; t < 16; t++) mk = key[t] < mk ? key[t] : mk;
#pragma unroll
        for (int o = 32; o; o >>= 1) {
            unsigned lo = __shfl_xor((unsigned)mk, o);
            unsigned hi = __shfl_xor((unsigned)(mk >> 32), o);
            unsigned long long ot = ((unsigned long long)hi << 32) | lo;
            mk = ot < mk ? ot : mk;
        }
        int m = (int)(mk & 0xffffffffu);
        if (lane == 0) out[sel] = m;
#pragma unroll
        for (int t = 0; t < 16; t++)
            if (m == t * 64 + lane) key[t] = ~0ull;
    }
}

// ---------------------------------------------------------------- knn attention
// block = one (b,n); threads = (h,d) = 8x32. hkv rows gathered by index.
template <int KK>
__global__ __launch_bounds__(256) void k_attn(const float* __restrict__ hq, const float* __restrict__ hkv,
                                              const int* __restrict__ kidx, float* __restrict__ out) {
    int bn = blockIdx.x;
    int b = bn >> 10;
    int tid = threadIdx.x;
    int h = tid >> 5, d = tid & 31;
    __shared__ float sa[8][64];
    __shared__ int si[64];
    if (tid < KK) si[tid] = kidx[(size_t)bn * KK + tid];
    __syncthreads();
    float qv = hq[(size_t)bn * 256 + tid] * 0.17677669529663689f;  // DH^-0.5
    for (int s = 0; s < KK; s++) {
        float kv = hkv[((size_t)b * 1024 + si[s]) * 512 + tid];
        float sc = qv * kv;
#pragma unroll
        for (int o = 16; o; o >>= 1) sc += __shfl_xor(sc, o, 32);
        if (d == 0) sa[h][s] = sc;
    }
    // softmax over s within the 32-lane head group (same wave -> no barrier needed)
    float mx = -1e30f;
    for (int s = d; s < KK; s += 32) mx = fmaxf(mx, sa[h][s]);
#pragma unroll
    for (int o = 16; o; o >>= 1) mx = fmaxf(mx, __shfl_xor(mx, o, 32));
    float sum = 0.0f;
    for (int s = d; s < KK; s += 32) {
        float e = __expf(sa[h][s] - mx);
        sa[h][s] = e;
        sum += e;
    }
#pragma unroll
    for (int o = 16; o; o >>= 1) sum += __shfl_xor(sum, o, 32);
    float inv = 1.0f / sum;
    float acc = 0.0f;
    for (int s = 0; s < KK; s++) {
        float vv = hkv[((size_t)b * 1024 + si[s]) * 512 + 256 + tid];
        acc += sa[h][s] * vv;
    }
    out[(size_t)bn * 256 + tid] = acc * inv;
}

// ------------------------------------------------- ms-deform sampling
// block = one (b,n); threads = (h,d) = 8x32; value row = 256 f32 (h*32+d)
__global__ __launch_bounds__(256) void k_msdeform(const float* __restrict__ offb, const float* __restrict__ awb,
                                                  const float* __restrict__ cpos, const float* __restrict__ value,
                                                  float* __restrict__ out) {
    int bn = blockIdx.x;
    int b = bn >> 10;
    int tid = threadIdx.x;
    int h = tid >> 5;
    __shared__ float aw[216];
    if (tid < 216) aw[tid] = awb[(size_t)bn * 216 + tid];
    __syncthreads();
    if (tid < 8) {  // per-head softmax over 27 (L*P jointly)
        float mx = -1e30f;
        for (int p = 0; p < 27; p++) mx = fmaxf(mx, aw[tid * 27 + p]);
        float s = 0.0f;
        for (int p = 0; p < 27; p++) {
            float e = __expf(aw[tid * 27 + p] - mx);
            aw[tid * 27 + p] = e;
            s += e;
        }
        float inv = 1.0f / s;
        for (int p = 0; p < 27; p++) aw[tid * 27 + p] *= inv;
    }
    __syncthreads();
    const float* offr = offb + (size_t)bn * 432 + h * 54;  // (h,l,p,2)
    const float* vb = value + (size_t)b * 21504 * 256;
    const int dims[3] = {128, 64, 32};
    const int starts[3] = {0, 16384, 20480};
    float acc = 0.0f;
#pragma unroll
    for (int l = 0; l < 3; l++) {
        int Wl = dims[l];
        int st = starts[l];
        float rx = cpos[(size_t)bn * 6 + l * 2], ry = cpos[(size_t)bn * 6 + l * 2 + 1];
        float rw = 1.0f / (float)Wl;  // exact (pow2)
#pragma unroll
        for (int p = 0; p < 9; p++) {
            float ox = offr[l * 18 + p * 2], oy = offr[l * 18 + p * 2 + 1];
            float xf = (rx + ox * rw) * (float)Wl - 0.5f;
            float yf = (ry + oy * rw) * (float)Wl - 0.5f;
            float x0 = floorf(xf), y0 = floorf(yf);
            float wgt = aw[h * 27 + l * 9 + p];
#pragma unroll
            for (int cy = 0; cy < 2; cy++) {
#pragma unroll
                for (int cx = 0; cx < 2; cx++) {
                    float ix = x0 + cx, iy = y0 + cy;
                    float w = (1.0f - fabsf(xf - ix)) * (1.0f - fabsf(yf - iy));
                    if (ix >= 0.0f && ix <= (float)(Wl - 1) && iy >= 0.0f && iy <= (float)(Wl - 1) && w != 0.0f) {
                        int flat = st + (int)iy * Wl + (int)ix;
                        acc += (w * wgt) * vb[(size_t)flat * 256 + tid];
                    }
                }
            }
        }
    }
    out[(size_t)bn * 256 + tid] = acc;
}

// ---------------------------------------------------------------- fp32 GEMM
// C[M,Ncol] = act( A'[M,K] @ B[K,Ncol] + bias ) + res
// A' = (A - mean)*rstd*g + b per-row if LNA.  64x64 tile, 4x4 microtile.
// Requires: M%64==0, K%16==0, Ncol%4==0.
template <bool LNA, bool BIAS, bool GELU, bool RES>
__global__ __launch_bounds__(256) void k_gemm(const float* __restrict__ A, const float* __restrict__ Bw,
                                              const float* __restrict__ bias, const float* res,
                                              const float* __restrict__ stats, const float* __restrict__ lng,
                                              const float* __restrict__ lnb, float* C, int M, int K, int Ncol) {
    __shared__ float As[16][64];  // [k][m]
    __shared__ float Bs[16][64];  // [k][n]
    int tid = threadIdx.x;
    int tx = tid & 15, ty = tid >> 4;
    int ar = tid >> 2, ak = (tid & 3) << 2;
    int am = blockIdx.y * 64 + ar;
    int bn = blockIdx.x * 64 + (tx << 2);
    float mean = 0.0f, rstd = 0.0f;
    if (LNA) {
        mean = stats[(size_t)am * 2];
        rstd = stats[(size_t)am * 2 + 1];
    }
    float acc[4][4] = {};
    const float* Ap = A + (size_t)am * K;
    for (int k0 = 0; k0 < K; k0 += 16) {
        float4 av = *(const float4*)(Ap + k0 + ak);
        if (LNA) {
            float4 gg = *(const float4*)(lng + k0 + ak);
            float4 bv = *(const float4*)(lnb + k0 + ak);
            av.x = (av.x - mean) * rstd * gg.x + bv.x;
            av.y = (av.y - mean) * rstd * gg.y + bv.y;
            av.z = (av.z - mean) * rstd * gg.z + bv.z;
            av.w = (av.w - mean) * rstd * gg.w + bv.w;
        }
        As[ak + 0][ar] = av.x;
        As[ak + 1][ar] = av.y;
        As[ak + 2][ar] = av.z;
        As[ak + 3][ar] = av.w;
        float4 bv4 = make_float4(0.f, 0.f, 0.f, 0.f);
        if (bn < Ncol) bv4 = *(const float4*)(Bw + (size_t)(k0 + ty) * Ncol + bn);
        *(float4*)&Bs[ty][tx << 2] = bv4;
        __syncthreads();
#pragma unroll
        for (int kk = 0; kk < 16; kk++) {
            float4 a4 = *(const float4*)&As[kk][ty << 2];
            float4 b4 = *(const float4*)&Bs[kk][tx << 2];
            float aa[4] = {a4.x, a4.y, a4.z, a4.w};
            float bb[4] = {b4.x, b4.y, b4.z, b4.w};
#pragma unroll
            for (int i = 0; i < 4; i++)
#pragma unroll
                for (int j = 0; j < 4; j++) acc[i][j] = fmaf(aa[i], bb[j], acc[i][j]);
        }
        __syncthreads();
    }
    int row0 = blockIdx.y * 64 + (ty << 2), col0 = blockIdx.x * 64 + (tx << 2);
    if (col0 >= Ncol) return;
    float4 bias4 = make_float4(0.f, 0.f, 0.f, 0.f);
    if (BIAS) bias4 = *(const float4*)(bias + col0);
#pragma unroll
    for (int i = 0; i < 4; i++) {
        size_t off = (size_t)(row0 + i) * Ncol + col0;
        float4 o;
        o.x = acc[i][0] + bias4.x;
        o.y = acc[i][1] + bias4.y;
        o.z = acc[i][2] + bias4.z;
        o.w = acc[i][3] + bias4.w;
        if (GELU) {
            o.x = gelu_f(o.x); o.y = gelu_f(o.y); o.z = gelu_f(o.z); o.w = gelu_f(o.w);
        }
        if (RES) {
            float4 r = *(const float4*)(res + off);
            o.x += r.x; o.y += r.y; o.z += r.z; o.w += r.w;
        }
        *(float4*)(C + off) = o;
    }
}

// ================================================================ launch
extern "C" void kernel_launch(void* const* d_in, const int* in_sizes, int n_in, void* d_out, int out_size,
                              void* d_ws, size_t ws_size, hipStream_t stream) {
    const float* xin = (const float*)d_in[0];
    const float* src = (const float*)d_in[1];
    const float* cpos = (const float*)d_in[2];
    const float* pos3 = (const float*)d_in[3];
    const float* Wpos = (const float*)d_in[6];
    const float* bpos = (const float*)d_in[7];
    const float* ln1g = (const float*)d_in[8];
    const float* ln1b = (const float*)d_in[9];
    const float* ln2g = (const float*)d_in[10];
    const float* ln2b = (const float*)d_in[11];
    const float* ln3g = (const float*)d_in[12];
    const float* ln3b = (const float*)d_in[13];
    const float* Wq = (const float*)d_in[14];
    const float* Wkv = (const float*)d_in[15];
    const float* Wosa = (const float*)d_in[16];
    const float* bosa = (const float*)d_in[17];
    const float* Wval = (const float*)d_in[18];
    const float* bval = (const float*)d_in[19];
    const float* Woff = (const float*)d_in[20];
    const float* boff = (const float*)d_in[21];
    const float* Waw = (const float*)d_in[22];
    const float* baw = (const float*)d_in[23];
    const float* Woca = (const float*)d_in[24];
    const float* boca = (const float*)d_in[25];
    const float* W1 = (const float*)d_in[26];
    const float* b1 = (const float*)d_in[27];
    const float* W2 = (const float*)d_in[28];
    const float* b2 = (const float*)d_in[29];
    float* x = (float*)d_out;

    float* ws = (float*)d_ws;
    float* sstats = ws;                    // 86016 (43008 rows * 2)
    float* cpe = sstats + 86016;           // 524288
    float* hbuf = cpe + 524288;            // 524288
    float* hq = hbuf + 524288;             // 524288
    float* hkv = hq + 524288;              // 1048576
    float* attn_o = hkv + 1048576;         // 524288
    float* qbuf = attn_o + 524288;         // 524288
    float* offb = qbuf + 524288;           // 884736 (2*1024*432)
    float* awb = offb + 884736;            // 442368 (2*1024*216)
    float* cab = awb + 442368;             // 524288
    float* ffmid = cab + 524288;           // 1048576
    float* value = ffmid + 1048576;        // 11010048 (2*21504*256)
    int* kidx = (int*)(value + 11010048);  // 131072 ints

    k_copy<<<512, 256, 0, stream>>>((const float4*)xin, (float4*)x, 131072);
    k_rowstats<<<10752, 256, 0, stream>>>(src, sstats);
    k_cpe<<<2048, 256, 0, stream>>>(cpos, Wpos, bpos, cpe);

    for (int i = 0; i < 2; i++) {
        // ---- self-attention (KNN) ----
        k_lnfused<<<512, 256, 0, stream>>>(x, cpe, nullptr, ln1g + i * 256, ln1b + i * 256, hbuf);
        if (i == 0)
            k_knn<16><<<512, 256, 0, stream>>>(pos3, kidx);
        else
            k_knn<64><<<512, 256, 0, stream>>>(pos3, kidx);
        k_gemm<false, false, false, false><<<dim3(4, 32), 256, 0, stream>>>(
            hbuf, Wq + i * 65536, nullptr, nullptr, nullptr, nullptr, nullptr, hq, 2048, 256, 256);
        k_gemm<false, false, false, false><<<dim3(8, 32), 256, 0, stream>>>(
            hbuf, Wkv + i * 131072, nullptr, nullptr, nullptr, nullptr, nullptr, hkv, 2048, 256, 512);
        if (i == 0)
            k_attn<16><<<2048, 256, 0, stream>>>(hq, hkv, kidx, attn_o);
        else
            k_attn<64><<<2048, 256, 0, stream>>>(hq, hkv, kidx, attn_o);
        k_gemm<false, true, false, true><<<dim3(4, 32), 256, 0, stream>>>(
            attn_o, Wosa + i * 65536, bosa + i * 256, x, nullptr, nullptr, nullptr, x, 2048, 256, 256);

        // ---- ms-deform cross-attention ----
        k_lnfused<<<512, 256, 0, stream>>>(x, nullptr, cpe, ln2g + i * 256, ln2b + i * 256, qbuf);
        k_gemm<true, true, false, false><<<dim3(4, 672), 256, 0, stream>>>(
            src, Wval + i * 65536, bval + i * 256, nullptr, sstats, ln2g + i * 256, ln2b + i * 256, value, 43008, 256, 256);
        k_gemm<false, true, false, false><<<dim3(7, 32), 256, 0, stream>>>(
            qbuf, Woff + i * 110592, boff + i * 432, nullptr, nullptr, nullptr, nullptr, offb, 2048, 256, 432);
        k_gemm<false, true, false, false><<<dim3(4, 32), 256, 0, stream>>>(
            qbuf, Waw + i * 55296, baw + i * 216, nullptr, nullptr, nullptr, nullptr, awb, 2048, 256, 216);
        k_msdeform<<<2048, 256, 0, stream>>>(offb, awb, cpos, value, cab);
        k_gemm<false, true, false, true><<<dim3(4, 32), 256, 0, stream>>>(
            cab, Woca + i * 65536, boca + i * 256, x, nullptr, nullptr, nullptr, x, 2048, 256, 256);

        // ---- FFN ----
        k_lnfused<<<512, 256, 0, stream>>>(x, nullptr, nullptr, ln3g + i * 256, ln3b + i * 256, hbuf);
        k_gemm<false, true, true, false><<<dim3(8, 32), 256, 0, stream>>>(
            hbuf, W1 + i * 131072, b1 + i * 512, nullptr, nullptr, nullptr, nullptr, ffmid, 2048, 256, 512);
        k_gemm<false, true, false, true><<<dim3(4, 32), 256, 0, stream>>>(
            ffmid, W2 + i * 131072, b2 + i * 256, x, nullptr, nullptr, nullptr, x, 2048, 512, 256);
    }
}

// Round 2
// 430.066 us; speedup vs baseline: 1.7769x; 1.7769x over previous
//
#include <hip/hip_runtime.h>
#include <math.h>

// Problem constants (hard-coded from reference)
// B=2, N=1024, C=256, HEADS=8, DH=32, INNER=256, L=3, P=9, FF=512, DEPTH=2
// LEN = 128*128 + 64*64 + 32*32 = 21504, level starts {0, 16384, 20480}

#define DEV __device__ __forceinline__

typedef __attribute__((ext_vector_type(8))) short bf16x8;
typedef __attribute__((ext_vector_type(4))) float floatx4;

DEV float gelu_f(float v) { return 0.5f * v * (1.0f + erff(v * 0.7071067811865475f)); }

DEV unsigned short f2bf(float f) {  // RTNE f32 -> bf16
    unsigned u = __float_as_uint(f);
    return (unsigned short)((u + 0x7fffu + ((u >> 16) & 1u)) >> 16);
}
DEV float bf2f(unsigned short s) { return __uint_as_float((unsigned)s << 16); }

// ---------------------------------------------------------------- copy x -> out
__global__ __launch_bounds__(256) void k_copy(const float4* __restrict__ a, float4* __restrict__ o, int n4) {
    int i = blockIdx.x * 256 + threadIdx.x;
    if (i < n4) o[i] = a[i];
}

// ------------------------------------------------- row stats (mean, rstd) of src
__global__ __launch_bounds__(256) void k_rowstats(const float* __restrict__ x, float* __restrict__ st) {
    int wid = threadIdx.x >> 6, lane = threadIdx.x & 63;
    size_t row = (size_t)blockIdx.x * 4 + wid;
    float4 v = ((const float4*)(x + row * 256))[lane];
    float s = (v.x + v.y) + (v.z + v.w);
#pragma unroll
    for (int o = 32; o; o >>= 1) s += __shfl_xor(s, o);
    float mean = s * (1.0f / 256.0f);
    float dx = v.x - mean, dy = v.y - mean, dz = v.z - mean, dw = v.w - mean;
    float q = (dx * dx + dy * dy) + (dz * dz + dw * dw);
#pragma unroll
    for (int o = 32; o; o >>= 1) q += __shfl_xor(q, o);
    if (lane == 0) {
        st[row * 2] = mean;
        st[row * 2 + 1] = 1.0f / sqrtf(q * (1.0f / 256.0f) + 1e-5f);
    }
}

// ---------------------------------------------------------------- cpe
__global__ __launch_bounds__(256) void k_cpe(const float* __restrict__ cpos, const float* __restrict__ Wp,
                                             const float* __restrict__ bp, float* __restrict__ cpe) {
    int bn = blockIdx.x, c = threadIdx.x;
    float px = cpos[(size_t)bn * 6 + 0], py = cpos[(size_t)bn * 6 + 1];
    cpe[(size_t)bn * 256 + c] = px * Wp[c] + py * Wp[256 + c] + bp[c];
}

// ------------------------------------------- out = LN(x [+pre]) * g + b [+post]
__global__ __launch_bounds__(256) void k_lnfused(const float* __restrict__ x, const float* pre, const float* post,
                                                 const float* __restrict__ g, const float* __restrict__ b,
                                                 float* __restrict__ out) {
    int wid = threadIdx.x >> 6, lane = threadIdx.x & 63;
    size_t row = (size_t)blockIdx.x * 4 + wid;
    float4 v = ((const float4*)(x + row * 256))[lane];
    if (pre) {
        float4 p = ((const float4*)(pre + row * 256))[lane];
        v.x += p.x; v.y += p.y; v.z += p.z; v.w += p.w;
    }
    float s = (v.x + v.y) + (v.z + v.w);
#pragma unroll
    for (int o = 32; o; o >>= 1) s += __shfl_xor(s, o);
    float mean = s * (1.0f / 256.0f);
    float dx = v.x - mean, dy = v.y - mean, dz = v.z - mean, dw = v.w - mean;
    float q = (dx * dx + dy * dy) + (dz * dz + dw * dw);
#pragma unroll
    for (int o = 32; o; o >>= 1) q += __shfl_xor(q, o);
    float rstd = 1.0f / sqrtf(q * (1.0f / 256.0f) + 1e-5f);
    float4 gg = ((const float4*)g)[lane], bb = ((const float4*)b)[lane];
    float4 o4;
    o4.x = dx * rstd * gg.x + bb.x;
    o4.y = dy * rstd * gg.y + bb.y;
    o4.z = dz * rstd * gg.z + bb.z;
    o4.w = dw * rstd * gg.w + bb.w;
    if (post) {
        float4 p = ((const float4*)(post + row * 256))[lane];
        o4.x += p.x; o4.y += p.y; o4.z += p.z; o4.w += p.w;
    }
    ((float4*)(out + row * 256))[lane] = o4;
}

// ---------------------------------------------------------------- KNN top-k (unchanged, verified)
template <int KK>
__global__ __launch_bounds__(256) void k_knn(const float* __restrict__ pos, int* __restrict__ kidx) {
    __shared__ float sp[3072];
    int b = blockIdx.x >> 8;
    int n0 = (blockIdx.x & 255) * 4;
    for (int t = threadIdx.x; t < 3072; t += 256) sp[t] = pos[(size_t)b * 3072 + t];
    __syncthreads();
    int wid = threadIdx.x >> 6, lane = threadIdx.x & 63;
    int n = n0 + wid;
    float qx = sp[n * 3], qy = sp[n * 3 + 1], qz = sp[n * 3 + 2];
    float sqn = (qx * qx + qy * qy) + qz * qz;
    unsigned long long key[16];
#pragma unroll
    for (int t = 0; t < 16; t++) {
        int m = t * 64 + lane;
        float mx = sp[m * 3], my = sp[m * 3 + 1], mz = sp[m * 3 + 2];
        float sqm = (mx * mx + my * my) + mz * mz;
        float dt = (qx * mx + qy * my) + qz * mz;
        float d2 = (sqn + sqm) - 2.0f * dt;
        unsigned u = __float_as_uint(d2);
        u = (u & 0x80000000u) ? ~u : (u | 0x80000000u);
        key[t] = ((unsigned long long)u << 32) | (unsigned)m;
    }
    int* out = kidx + ((size_t)b * 1024 + n) * KK;
    for (int sel = 0; sel < KK; sel++) {
        unsigned long long mk = key[0];
#pragma unroll
        for (int t = 1; t < 16; t++) mk = key[t] < mk ? key[t] : mk;
#pragma unroll
        for (int o = 32; o; o >>= 1) {
            unsigned lo = __shfl_xor((unsigned)mk, o);
            unsigned hi = __shfl_xor((unsigned)(mk >> 32), o);
            unsigned long long ot = ((unsigned long long)hi << 32) | lo;
            mk = ot < mk ? ot : mk;
        }
        int m = (int)(mk & 0xffffffffu);
        if (lane == 0) out[sel] = m;
#pragma unroll
        for (int t = 0; t < 16; t++)
            if (m == t * 64 + lane) key[t] = ~0ull;
    }
}

// ---------------------------------------------------------------- knn attention
template <int KK>
__global__ __launch_bounds__(256) void k_attn(const float* __restrict__ hq, const float* __restrict__ hkv,
                                              const int* __restrict__ kidx, float* __restrict__ out) {
    int bn = blockIdx.x;
    int b = bn >> 10;
    int tid = threadIdx.x;
    int h = tid >> 5, d = tid & 31;
    __shared__ float sa[8][64];
    __shared__ int si[64];
    if (tid < KK) si[tid] = kidx[(size_t)bn * KK + tid];
    __syncthreads();
    float qv = hq[(size_t)bn * 256 + tid] * 0.17677669529663689f;
    for (int s = 0; s < KK; s++) {
        float kv = hkv[((size_t)b * 1024 + si[s]) * 512 + tid];
        float sc = qv * kv;
#pragma unroll
        for (int o = 16; o; o >>= 1) sc += __shfl_xor(sc, o, 32);
        if (d == 0) sa[h][s] = sc;
    }
    float mx = -1e30f;
    for (int s = d; s < KK; s += 32) mx = fmaxf(mx, sa[h][s]);
#pragma unroll
    for (int o = 16; o; o >>= 1) mx = fmaxf(mx, __shfl_xor(mx, o, 32));
    float sum = 0.0f;
    for (int s = d; s < KK; s += 32) {
        float e = __expf(sa[h][s] - mx);
        sa[h][s] = e;
        sum += e;
    }
#pragma unroll
    for (int o = 16; o; o >>= 1) sum += __shfl_xor(sum, o, 32);
    float inv = 1.0f / sum;
    float acc = 0.0f;
    for (int s = 0; s < KK; s++) {
        float vv = hkv[((size_t)b * 1024 + si[s]) * 512 + 256 + tid];
        acc += sa[h][s] * vv;
    }
    out[(size_t)bn * 256 + tid] = acc * inv;
}

// ------------------------------------------------- ms-deform sampling (value is bf16 now)
__global__ __launch_bounds__(256) void k_msdeform(const float* __restrict__ offb, const float* __restrict__ awb,
                                                  const float* __restrict__ cpos, const unsigned short* __restrict__ value,
                                                  float* __restrict__ out) {
    int bn = blockIdx.x;
    int b = bn >> 10;
    int tid = threadIdx.x;
    int h = tid >> 5;
    __shared__ float aw[216];
    if (tid < 216) aw[tid] = awb[(size_t)bn * 216 + tid];
    __syncthreads();
    if (tid < 8) {
        float mx = -1e30f;
        for (int p = 0; p < 27; p++) mx = fmaxf(mx, aw[tid * 27 + p]);
        float s = 0.0f;
        for (int p = 0; p < 27; p++) {
            float e = __expf(aw[tid * 27 + p] - mx);
            aw[tid * 27 + p] = e;
            s += e;
        }
        float inv = 1.0f / s;
        for (int p = 0; p < 27; p++) aw[tid * 27 + p] *= inv;
    }
    __syncthreads();
    const float* offr = offb + (size_t)bn * 432 + h * 54;
    const unsigned short* vb = value + (size_t)b * 21504 * 256;
    const int dims[3] = {128, 64, 32};
    const int starts[3] = {0, 16384, 20480};
    float acc = 0.0f;
#pragma unroll
    for (int l = 0; l < 3; l++) {
        int Wl = dims[l];
        int st = starts[l];
        float rx = cpos[(size_t)bn * 6 + l * 2], ry = cpos[(size_t)bn * 6 + l * 2 + 1];
        float rw = 1.0f / (float)Wl;
#pragma unroll
        for (int p = 0; p < 9; p++) {
            float ox = offr[l * 18 + p * 2], oy = offr[l * 18 + p * 2 + 1];
            float xf = (rx + ox * rw) * (float)Wl - 0.5f;
            float yf = (ry + oy * rw) * (float)Wl - 0.5f;
            float x0 = floorf(xf), y0 = floorf(yf);
            float wgt = aw[h * 27 + l * 9 + p];
#pragma unroll
            for (int cy = 0; cy < 2; cy++) {
#pragma unroll
                for (int cx = 0; cx < 2; cx++) {
                    float ix = x0 + cx, iy = y0 + cy;
                    float w = (1.0f - fabsf(xf - ix)) * (1.0f - fabsf(yf - iy));
                    if (ix >= 0.0f && ix <= (float)(Wl - 1) && iy >= 0.0f && iy <= (float)(Wl - 1) && w != 0.0f) {
                        int flat = st + (int)iy * Wl + (int)ix;
                        acc += (w * wgt) * bf2f(vb[(size_t)flat * 256 + tid]);
                    }
                }
            }
        }
    }
    out[(size_t)bn * 256 + tid] = acc;
}

// ------------------------------------------- weight transpose+convert: W[K][N] f32 -> Wt[N][K] bf16
struct TJobs {
    const float* src[18];
    unsigned short* dst[18];
    int K[18];
    int N[18];
};
__global__ __launch_bounds__(256) void k_tw(TJobs j) {
    int job = blockIdx.z;
    int K = j.K[job], N = j.N[job];
    int nt = (N + 31) >> 5, kt = K >> 5;
    if ((int)blockIdx.x >= nt || (int)blockIdx.y >= kt) return;
    __shared__ float t[32][33];
    const float* W = j.src[job];
    unsigned short* Wt = j.dst[job];
    int x = threadIdx.x & 31, y = threadIdx.x >> 5;
    int n0 = blockIdx.x << 5, k0 = blockIdx.y << 5;
#pragma unroll
    for (int i = 0; i < 32; i += 8) {
        int n = n0 + x;
        t[y + i][x] = (n < N) ? W[(size_t)(k0 + y + i) * N + n] : 0.0f;
    }
    __syncthreads();
#pragma unroll
    for (int i = 0; i < 32; i += 8) {
        int n = n0 + y + i;
        if (n < N) Wt[(size_t)n * K + k0 + x] = f2bf(t[x][y + i]);
    }
}

// ---------------------------------------------------------------- bf16 MFMA GEMM
// C[M,N] = act( A'[M,K] @ W[K,N] + bias ) (+res).  W passed as Wt[N][K] bf16.
// A' = (A-mean)*rstd*g+b per row if LNA. BM=64 fixed, BK=32, 256 thr = 4 waves.
// Requires M%64==0, K%32==0. N arbitrary (guarded).
template <int BN, int WGM, int WGN, bool LNA, bool BIAS, bool GELUF, bool RES, bool OBF16>
__global__ __launch_bounds__(256) void k_mgemm(const float* __restrict__ A, const unsigned short* __restrict__ Bt,
                                               const float* __restrict__ bias, const float* __restrict__ res,
                                               const float* __restrict__ stats, const float* __restrict__ lng,
                                               const float* __restrict__ lnb, void* __restrict__ Cout,
                                               int M, int K, int Ncol) {
    constexpr int BM = 64, BK = 32;
    constexpr int WAVE_M = BM / WGM, WAVE_N = BN / WGN;
    constexpr int FM = WAVE_M / 16, FN = WAVE_N / 16;
    constexpr int BUN = BN / 64;  // 16B B-units per thread
    __shared__ __align__(16) short a_lds[4][BM][8];
    __shared__ __align__(16) short b_lds[4][BN][8];
    int tid = threadIdx.x;
    int am0 = blockIdx.y * BM, bn0 = blockIdx.x * BN;
    // --- staging coords (A: 1 unit/thread) ---
    int ar = tid >> 2, akc = tid & 3;
    const float* Arow = A + (size_t)(am0 + ar) * K + akc * 8;
    float mean = 0.0f, rstd = 0.0f;
    if (LNA) {
        mean = stats[(size_t)(am0 + ar) * 2];
        rstd = stats[(size_t)(am0 + ar) * 2 + 1];
    }
    float4 a0, a1, g0, g1, c0, c1;
    int4 bq[BUN];
    int nsteps = K / BK;

    auto load_tile = [&](int k0) {
        a0 = *(const float4*)(Arow + k0);
        a1 = *(const float4*)(Arow + k0 + 4);
        if (LNA) {
            g0 = *(const float4*)(lng + k0 + akc * 8);
            g1 = *(const float4*)(lng + k0 + akc * 8 + 4);
            c0 = *(const float4*)(lnb + k0 + akc * 8);
            c1 = *(const float4*)(lnb + k0 + akc * 8 + 4);
        }
#pragma unroll
        for (int jj = 0; jj < BUN; jj++) {
            int u = tid + 256 * jj;
            int col = u >> 2, kc = u & 3;
            int gn = bn0 + col;
            if (gn < Ncol)
                bq[jj] = *(const int4*)(Bt + (size_t)gn * K + k0 + kc * 8);
            else
                bq[jj] = make_int4(0, 0, 0, 0);
        }
    };
    auto write_lds = [&]() {
        float v[8] = {a0.x, a0.y, a0.z, a0.w, a1.x, a1.y, a1.z, a1.w};
        if (LNA) {
            float gg[8] = {g0.x, g0.y, g0.z, g0.w, g1.x, g1.y, g1.z, g1.w};
            float bb[8] = {c0.x, c0.y, c0.z, c0.w, c1.x, c1.y, c1.z, c1.w};
#pragma unroll
            for (int e = 0; e < 8; e++) v[e] = (v[e] - mean) * rstd * gg[e] + bb[e];
        }
        bf16x8 pk;
#pragma unroll
        for (int e = 0; e < 8; e++) pk[e] = (short)f2bf(v[e]);
        *(bf16x8*)(&a_lds[akc][ar][0]) = pk;
#pragma unroll
        for (int jj = 0; jj < BUN; jj++) {
            int u = tid + 256 * jj;
            int col = u >> 2, kc = u & 3;
            *(int4*)(&b_lds[kc][col][0]) = bq[jj];
        }
    };
    // --- compute coords ---
    int lane = tid & 63, wid = tid >> 6;
    int wm = wid / WGN, wn = wid % WGN;
    int fr = lane & 15, fkc = lane >> 4;
    floatx4 acc[FM][FN] = {};

    load_tile(0);
    for (int t = 0; t < nsteps; ++t) {
        if (t) __syncthreads();
        write_lds();
        __syncthreads();
        if (t + 1 < nsteps) load_tile((t + 1) * BK);
        bf16x8 af[FM], bf[FN];
#pragma unroll
        for (int m = 0; m < FM; m++) af[m] = *(const bf16x8*)(&a_lds[fkc][wm * WAVE_M + m * 16 + fr][0]);
#pragma unroll
        for (int n = 0; n < FN; n++) bf[n] = *(const bf16x8*)(&b_lds[fkc][wn * WAVE_N + n * 16 + fr][0]);
#pragma unroll
        for (int m = 0; m < FM; m++)
#pragma unroll
            for (int n = 0; n < FN; n++)
                acc[m][n] = __builtin_amdgcn_mfma_f32_16x16x32_bf16(af[m], bf[n], acc[m][n], 0, 0, 0);
    }
    // --- epilogue: C/D layout col=lane&15, row=(lane>>4)*4+reg ---
    int r4 = lane >> 4;
#pragma unroll
    for (int m = 0; m < FM; m++) {
        int row = am0 + wm * WAVE_M + m * 16 + r4 * 4;
#pragma unroll
        for (int n = 0; n < FN; n++) {
            int col = bn0 + wn * WAVE_N + n * 16 + fr;
            if (col < Ncol) {
                float bsc = BIAS ? bias[col] : 0.0f;
#pragma unroll
                for (int r = 0; r < 4; r++) {
                    size_t off = (size_t)(row + r) * Ncol + col;
                    float v = acc[m][n][r] + bsc;
                    if (GELUF) v = gelu_f(v);
                    if (RES) v += res[off];
                    if (OBF16)
                        ((unsigned short*)Cout)[off] = f2bf(v);
                    else
                        ((float*)Cout)[off] = v;
                }
            }
        }
    }
}

// ================================================================ launch
extern "C" void kernel_launch(void* const* d_in, const int* in_sizes, int n_in, void* d_out, int out_size,
                              void* d_ws, size_t ws_size, hipStream_t stream) {
    const float* xin = (const float*)d_in[0];
    const float* src = (const float*)d_in[1];
    const float* cpos = (const float*)d_in[2];
    const float* pos3 = (const float*)d_in[3];
    const float* Wpos = (const float*)d_in[6];
    const float* bpos = (const float*)d_in[7];
    const float* ln1g = (const float*)d_in[8];
    const float* ln1b = (const float*)d_in[9];
    const float* ln2g = (const float*)d_in[10];
    const float* ln2b = (const float*)d_in[11];
    const float* ln3g = (const float*)d_in[12];
    const float* ln3b = (const float*)d_in[13];
    const float* Wq = (const float*)d_in[14];
    const float* Wkv = (const float*)d_in[15];
    const float* Wosa = (const float*)d_in[16];
    const float* bosa = (const float*)d_in[17];
    const float* Wval = (const float*)d_in[18];
    const float* bval = (const float*)d_in[19];
    const float* Woff = (const float*)d_in[20];
    const float* boff = (const float*)d_in[21];
    const float* Waw = (const float*)d_in[22];
    const float* baw = (const float*)d_in[23];
    const float* Woca = (const float*)d_in[24];
    const float* boca = (const float*)d_in[25];
    const float* W1 = (const float*)d_in[26];
    const float* b1 = (const float*)d_in[27];
    const float* W2 = (const float*)d_in[28];
    const float* b2 = (const float*)d_in[29];
    float* x = (float*)d_out;

    float* ws = (float*)d_ws;
    float* sstats = ws;                     // 86016
    float* cpe = sstats + 86016;            // 524288
    float* hbuf = cpe + 524288;             // 524288
    float* hq = hbuf + 524288;              // 524288
    float* hkv = hq + 524288;               // 1048576
    float* attn_o = hkv + 1048576;          // 524288
    float* qbuf = attn_o + 524288;          // 524288
    float* offb = qbuf + 524288;            // 884736
    float* awb = offb + 884736;             // 442368
    float* cab = awb + 442368;              // 524288
    float* ffmid = cab + 524288;            // 1048576
    unsigned short* value = (unsigned short*)(ffmid + 1048576);  // 11010048 shorts (5505024 f32 slots)
    int* kidx = (int*)(ffmid + 1048576 + 5505024);               // 131072 ints
    unsigned short* wt = (unsigned short*)(kidx + 131072);       // 1642496 shorts

    // per-depth bf16 transposed weight offsets within wt
    const size_t WT_STRIDE = 821248;
    const size_t O_WQ = 0, O_WKV = 65536, O_WOSA = 196608, O_WVAL = 262144, O_WOFF = 327680,
                 O_WAW = 438272, O_WOCA = 493568, O_W1 = 559104, O_W2 = 690176;

    // fill transpose jobs (9 weights x 2 depths)
    TJobs tj;
    for (int d = 0; d < 2; d++) {
        int base = d * 9;
        unsigned short* wd = wt + (size_t)d * WT_STRIDE;
        tj.src[base + 0] = Wq + (size_t)d * 65536;   tj.dst[base + 0] = wd + O_WQ;   tj.K[base + 0] = 256; tj.N[base + 0] = 256;
        tj.src[base + 1] = Wkv + (size_t)d * 131072; tj.dst[base + 1] = wd + O_WKV;  tj.K[base + 1] = 256; tj.N[base + 1] = 512;
        tj.src[base + 2] = Wosa + (size_t)d * 65536; tj.dst[base + 2] = wd + O_WOSA; tj.K[base + 2] = 256; tj.N[base + 2] = 256;
        tj.src[base + 3] = Wval + (size_t)d * 65536; tj.dst[base + 3] = wd + O_WVAL; tj.K[base + 3] = 256; tj.N[base + 3] = 256;
        tj.src[base + 4] = Woff + (size_t)d * 110592; tj.dst[base + 4] = wd + O_WOFF; tj.K[base + 4] = 256; tj.N[base + 4] = 432;
        tj.src[base + 5] = Waw + (size_t)d * 55296;  tj.dst[base + 5] = wd + O_WAW;  tj.K[base + 5] = 256; tj.N[base + 5] = 216;
        tj.src[base + 6] = Woca + (size_t)d * 65536; tj.dst[base + 6] = wd + O_WOCA; tj.K[base + 6] = 256; tj.N[base + 6] = 256;
        tj.src[base + 7] = W1 + (size_t)d * 131072;  tj.dst[base + 7] = wd + O_W1;   tj.K[base + 7] = 256; tj.N[base + 7] = 512;
        tj.src[base + 8] = W2 + (size_t)d * 131072;  tj.dst[base + 8] = wd + O_W2;   tj.K[base + 8] = 512; tj.N[base + 8] = 256;
    }
    k_tw<<<dim3(16, 16, 18), 256, 0, stream>>>(tj);

    k_copy<<<512, 256, 0, stream>>>((const float4*)xin, (float4*)x, 131072);
    k_rowstats<<<10752, 256, 0, stream>>>(src, sstats);
    k_cpe<<<2048, 256, 0, stream>>>(cpos, Wpos, bpos, cpe);

    for (int i = 0; i < 2; i++) {
        unsigned short* wd = wt + (size_t)i * WT_STRIDE;
        // ---- self-attention (KNN) ----
        k_lnfused<<<512, 256, 0, stream>>>(x, cpe, nullptr, ln1g + i * 256, ln1b + i * 256, hbuf);
        if (i == 0)
            k_knn<16><<<512, 256, 0, stream>>>(pos3, kidx);
        else
            k_knn<64><<<512, 256, 0, stream>>>(pos3, kidx);
        k_mgemm<64, 2, 2, false, false, false, false, false><<<dim3(4, 32), 256, 0, stream>>>(
            hbuf, wd + O_WQ, nullptr, nullptr, nullptr, nullptr, nullptr, hq, 2048, 256, 256);
        k_mgemm<64, 2, 2, false, false, false, false, false><<<dim3(8, 32), 256, 0, stream>>>(
            hbuf, wd + O_WKV, nullptr, nullptr, nullptr, nullptr, nullptr, hkv, 2048, 256, 512);
        if (i == 0)
            k_attn<16><<<2048, 256, 0, stream>>>(hq, hkv, kidx, attn_o);
        else
            k_attn<64><<<2048, 256, 0, stream>>>(hq, hkv, kidx, attn_o);
        k_mgemm<64, 2, 2, false, true, false, true, false><<<dim3(4, 32), 256, 0, stream>>>(
            attn_o, wd + O_WOSA, bosa + i * 256, x, nullptr, nullptr, nullptr, x, 2048, 256, 256);

        // ---- ms-deform cross-attention ----
        k_lnfused<<<512, 256, 0, stream>>>(x, nullptr, cpe, ln2g + i * 256, ln2b + i * 256, qbuf);
        k_mgemm<256, 1, 4, true, true, false, false, true><<<dim3(1, 672), 256, 0, stream>>>(
            src, wd + O_WVAL, bval + i * 256, nullptr, sstats, ln2g + i * 256, ln2b + i * 256, value, 43008, 256, 256);
        k_mgemm<64, 2, 2, false, true, false, false, false><<<dim3(7, 32), 256, 0, stream>>>(
            qbuf, wd + O_WOFF, boff + i * 432, nullptr, nullptr, nullptr, nullptr, offb, 2048, 256, 432);
        k_mgemm<64, 2, 2, false, true, false, false, false><<<dim3(4, 32), 256, 0, stream>>>(
            qbuf, wd + O_WAW, baw + i * 216, nullptr, nullptr, nullptr, nullptr, awb, 2048, 256, 216);
        k_msdeform<<<2048, 256, 0, stream>>>(offb, awb, cpos, value, cab);
        k_mgemm<64, 2, 2, false, true, false, true, false><<<dim3(4, 32), 256, 0, stream>>>(
            cab, wd + O_WOCA, boca + i * 256, x, nullptr, nullptr, nullptr, x, 2048, 256, 256);

        // ---- FFN ----
        k_lnfused<<<512, 256, 0, stream>>>(x, nullptr, nullptr, ln3g + i * 256, ln3b + i * 256, hbuf);
        k_mgemm<64, 2, 2, false, true, true, false, false><<<dim3(8, 32), 256, 0, stream>>>(
            hbuf, wd + O_W1, b1 + i * 512, nullptr, nullptr, nullptr, nullptr, ffmid, 2048, 256, 512);
        k_mgemm<64, 2, 2, false, true, false, true, false><<<dim3(4, 32), 256, 0, stream>>>(
            ffmid, wd + O_W2, b2 + i * 256, x, nullptr, nullptr, nullptr, x, 2048, 512, 256);
    }
}

// Round 3
// 379.789 us; speedup vs baseline: 2.0122x; 1.1324x over previous
//
#include <hip/hip_runtime.h>
#include <math.h>

// Problem constants (hard-coded from reference)
// B=2, N=1024, C=256, HEADS=8, DH=32, INNER=256, L=3, P=9, FF=512, DEPTH=2
// LEN = 128*128 + 64*64 + 32*32 = 21504, level starts {0, 16384, 20480}

#define DEV __device__ __forceinline__

typedef __attribute__((ext_vector_type(8))) short bf16x8;
typedef __attribute__((ext_vector_type(4))) float floatx4;

DEV float gelu_f(float v) { return 0.5f * v * (1.0f + erff(v * 0.7071067811865475f)); }

DEV unsigned short f2bf(float f) {  // RTNE f32 -> bf16
    unsigned u = __float_as_uint(f);
    return (unsigned short)((u + 0x7fffu + ((u >> 16) & 1u)) >> 16);
}
DEV float bf2f(unsigned short s) { return __uint_as_float((unsigned)s << 16); }

// ---------------------------------------------------------------- copy x -> out
__global__ __launch_bounds__(256) void k_copy(const float4* __restrict__ a, float4* __restrict__ o, int n4) {
    int i = blockIdx.x * 256 + threadIdx.x;
    if (i < n4) o[i] = a[i];
}

// ------------------------------------------------- row stats (mean, rstd) of src
__global__ __launch_bounds__(256) void k_rowstats(const float* __restrict__ x, float* __restrict__ st) {
    int wid = threadIdx.x >> 6, lane = threadIdx.x & 63;
    size_t row = (size_t)blockIdx.x * 4 + wid;
    float4 v = ((const float4*)(x + row * 256))[lane];
    float s = (v.x + v.y) + (v.z + v.w);
#pragma unroll
    for (int o = 32; o; o >>= 1) s += __shfl_xor(s, o);
    float mean = s * (1.0f / 256.0f);
    float dx = v.x - mean, dy = v.y - mean, dz = v.z - mean, dw = v.w - mean;
    float q = (dx * dx + dy * dy) + (dz * dz + dw * dw);
#pragma unroll
    for (int o = 32; o; o >>= 1) q += __shfl_xor(q, o);
    if (lane == 0) {
        st[row * 2] = mean;
        st[row * 2 + 1] = 1.0f / sqrtf(q * (1.0f / 256.0f) + 1e-5f);
    }
}

// ---------------------------------------------------------------- cpe
__global__ __launch_bounds__(256) void k_cpe(const float* __restrict__ cpos, const float* __restrict__ Wp,
                                             const float* __restrict__ bp, float* __restrict__ cpe) {
    int bn = blockIdx.x, c = threadIdx.x;
    float px = cpos[(size_t)bn * 6 + 0], py = cpos[(size_t)bn * 6 + 1];
    cpe[(size_t)bn * 256 + c] = px * Wp[c] + py * Wp[256 + c] + bp[c];
}

// ------------------------------------------- out = LN(x [+pre]) * g + b [+post]
__global__ __launch_bounds__(256) void k_lnfused(const float* __restrict__ x, const float* pre, const float* post,
                                                 const float* __restrict__ g, const float* __restrict__ b,
                                                 float* __restrict__ out) {
    int wid = threadIdx.x >> 6, lane = threadIdx.x & 63;
    size_t row = (size_t)blockIdx.x * 4 + wid;
    float4 v = ((const float4*)(x + row * 256))[lane];
    if (pre) {
        float4 p = ((const float4*)(pre + row * 256))[lane];
        v.x += p.x; v.y += p.y; v.z += p.z; v.w += p.w;
    }
    float s = (v.x + v.y) + (v.z + v.w);
#pragma unroll
    for (int o = 32; o; o >>= 1) s += __shfl_xor(s, o);
    float mean = s * (1.0f / 256.0f);
    float dx = v.x - mean, dy = v.y - mean, dz = v.z - mean, dw = v.w - mean;
    float q = (dx * dx + dy * dy) + (dz * dz + dw * dw);
#pragma unroll
    for (int o = 32; o; o >>= 1) q += __shfl_xor(q, o);
    float rstd = 1.0f / sqrtf(q * (1.0f / 256.0f) + 1e-5f);
    float4 gg = ((const float4*)g)[lane], bb = ((const float4*)b)[lane];
    float4 o4;
    o4.x = dx * rstd * gg.x + bb.x;
    o4.y = dy * rstd * gg.y + bb.y;
    o4.z = dz * rstd * gg.z + bb.z;
    o4.w = dw * rstd * gg.w + bb.w;
    if (post) {
        float4 p = ((const float4*)(post + row * 256))[lane];
        o4.x += p.x; o4.y += p.y; o4.z += p.z; o4.w += p.w;
    }
    ((float4*)(out + row * 256))[lane] = o4;
}

// ---------------------------------------------------------------- KNN top-k (unchanged, verified)
template <int KK>
__global__ __launch_bounds__(256) void k_knn(const float* __restrict__ pos, int* __restrict__ kidx) {
    __shared__ float sp[3072];
    int b = blockIdx.x >> 8;
    int n0 = (blockIdx.x & 255) * 4;
    for (int t = threadIdx.x; t < 3072; t += 256) sp[t] = pos[(size_t)b * 3072 + t];
    __syncthreads();
    int wid = threadIdx.x >> 6, lane = threadIdx.x & 63;
    int n = n0 + wid;
    float qx = sp[n * 3], qy = sp[n * 3 + 1], qz = sp[n * 3 + 2];
    float sqn = (qx * qx + qy * qy) + qz * qz;
    unsigned long long key[16];
#pragma unroll
    for (int t = 0; t < 16; t++) {
        int m = t * 64 + lane;
        float mx = sp[m * 3], my = sp[m * 3 + 1], mz = sp[m * 3 + 2];
        float sqm = (mx * mx + my * my) + mz * mz;
        float dt = (qx * mx + qy * my) + qz * mz;
        float d2 = (sqn + sqm) - 2.0f * dt;
        unsigned u = __float_as_uint(d2);
        u = (u & 0x80000000u) ? ~u : (u | 0x80000000u);
        key[t] = ((unsigned long long)u << 32) | (unsigned)m;
    }
    int* out = kidx + ((size_t)b * 1024 + n) * KK;
    for (int sel = 0; sel < KK; sel++) {
        unsigned long long mk = key[0];
#pragma unroll
        for (int t = 1; t < 16; t++) mk = key[t] < mk ? key[t] : mk;
#pragma unroll
        for (int o = 32; o; o >>= 1) {
            unsigned lo = __shfl_xor((unsigned)mk, o);
            unsigned hi = __shfl_xor((unsigned)(mk >> 32), o);
            unsigned long long ot = ((unsigned long long)hi << 32) | lo;
            mk = ot < mk ? ot : mk;
        }
        int m = (int)(mk & 0xffffffffu);
        if (lane == 0) out[sel] = m;
#pragma unroll
        for (int t = 0; t < 16; t++)
            if (m == t * 64 + lane) key[t] = ~0ull;
    }
}

// ---------------------------------------------------------------- knn attention
// hqkv[row][768]: q at 0, k at 256, v at 512.
// Phase 1 (scores): thread -> (h,s) pair, full 32-dot per thread, NO shuffles.
// Phase 2 (softmax): 32-lane group per head. Phase 3 (PV): (h,d) threads.
template <int KK>
__global__ __launch_bounds__(256) void k_attn(const float* __restrict__ hqkv, const int* __restrict__ kidx,
                                              float* __restrict__ out) {
    int bn = blockIdx.x;
    int b = bn >> 10;
    int tid = threadIdx.x;
    __shared__ float sq[256];
    __shared__ float sa[8][KK];
    __shared__ int si[KK];
    if (tid < KK) si[tid] = kidx[(size_t)bn * KK + tid];
    sq[tid] = hqkv[(size_t)bn * 768 + tid] * 0.17677669529663689f;  // DH^-0.5
    __syncthreads();
    const float* kvb = hqkv + (size_t)b * 1024 * 768;
#pragma unroll
    for (int pair = tid; pair < 8 * KK; pair += 256) {
        int s = pair & (KK - 1);
        int h = pair / KK;
        const float4* kr = (const float4*)(kvb + (size_t)si[s] * 768 + 256 + h * 32);
        const float4* q4 = (const float4*)&sq[h * 32];
        float a0 = 0.f, a1 = 0.f, a2 = 0.f, a3 = 0.f;
#pragma unroll
        for (int e = 0; e < 8; e++) {
            float4 kv = kr[e];
            float4 qv = q4[e];
            a0 = fmaf(kv.x, qv.x, a0);
            a1 = fmaf(kv.y, qv.y, a1);
            a2 = fmaf(kv.z, qv.z, a2);
            a3 = fmaf(kv.w, qv.w, a3);
        }
        sa[h][s] = (a0 + a1) + (a2 + a3);
    }
    __syncthreads();
    int h = tid >> 5, d = tid & 31;
    // softmax over s within the 32-lane head group
    float mx = -1e30f;
    for (int s = d; s < KK; s += 32) mx = fmaxf(mx, sa[h][s]);
#pragma unroll
    for (int o = 16; o; o >>= 1) mx = fmaxf(mx, __shfl_xor(mx, o, 32));
    float sum = 0.0f;
    for (int s = d; s < KK; s += 32) {
        float e = __expf(sa[h][s] - mx);
        sa[h][s] = e;
        sum += e;
    }
#pragma unroll
    for (int o = 16; o; o >>= 1) sum += __shfl_xor(sum, o, 32);
    float inv = 1.0f / sum;
    __syncthreads();
    float acc = 0.0f;
    for (int s = 0; s < KK; s++) {
        float vv = kvb[(size_t)si[s] * 768 + 512 + tid];
        acc += sa[h][s] * vv;
    }
    out[(size_t)bn * 256 + tid] = acc * inv;
}

// ------------------------------------------------- ms-deform sampling (value bf16; offaw concat [648])
__global__ __launch_bounds__(256) void k_msdeform(const float* __restrict__ offaw, const float* __restrict__ cpos,
                                                  const unsigned short* __restrict__ value, float* __restrict__ out) {
    int bn = blockIdx.x;
    int b = bn >> 10;
    int tid = threadIdx.x;
    int h = tid >> 5;
    __shared__ float aw[216];
    if (tid < 216) aw[tid] = offaw[(size_t)bn * 648 + 432 + tid];
    __syncthreads();
    if (tid < 8) {
        float mx = -1e30f;
        for (int p = 0; p < 27; p++) mx = fmaxf(mx, aw[tid * 27 + p]);
        float s = 0.0f;
        for (int p = 0; p < 27; p++) {
            float e = __expf(aw[tid * 27 + p] - mx);
            aw[tid * 27 + p] = e;
            s += e;
        }
        float inv = 1.0f / s;
        for (int p = 0; p < 27; p++) aw[tid * 27 + p] *= inv;
    }
    __syncthreads();
    const float* offr = offaw + (size_t)bn * 648 + h * 54;
    const unsigned short* vb = value + (size_t)b * 21504 * 256;
    const int dims[3] = {128, 64, 32};
    const int starts[3] = {0, 16384, 20480};
    float acc = 0.0f;
#pragma unroll
    for (int l = 0; l < 3; l++) {
        int Wl = dims[l];
        int st = starts[l];
        float rx = cpos[(size_t)bn * 6 + l * 2], ry = cpos[(size_t)bn * 6 + l * 2 + 1];
        float rw = 1.0f / (float)Wl;
#pragma unroll
        for (int p = 0; p < 9; p++) {
            float ox = offr[l * 18 + p * 2], oy = offr[l * 18 + p * 2 + 1];
            float xf = (rx + ox * rw) * (float)Wl - 0.5f;
            float yf = (ry + oy * rw) * (float)Wl - 0.5f;
            float x0 = floorf(xf), y0 = floorf(yf);
            float wgt = aw[h * 27 + l * 9 + p];
#pragma unroll
            for (int cy = 0; cy < 2; cy++) {
#pragma unroll
                for (int cx = 0; cx < 2; cx++) {
                    float ix = x0 + cx, iy = y0 + cy;
                    float w = (1.0f - fabsf(xf - ix)) * (1.0f - fabsf(yf - iy));
                    if (ix >= 0.0f && ix <= (float)(Wl - 1) && iy >= 0.0f && iy <= (float)(Wl - 1) && w != 0.0f) {
                        int flat = st + (int)iy * Wl + (int)ix;
                        acc += (w * wgt) * bf2f(vb[(size_t)flat * 256 + tid]);
                    }
                }
            }
        }
    }
    out[(size_t)bn * 256 + tid] = acc;
}

// ------------------------------------------- weight transpose+convert: W[K][N] f32 -> Wt[N][K] bf16
struct TJobs {
    const float* src[18];
    unsigned short* dst[18];
    int K[18];
    int N[18];
};
__global__ __launch_bounds__(256) void k_tw(TJobs j) {
    int job = blockIdx.z;
    int K = j.K[job], N = j.N[job];
    int nt = (N + 31) >> 5, kt = K >> 5;
    if ((int)blockIdx.x >= nt || (int)blockIdx.y >= kt) return;
    __shared__ float t[32][33];
    const float* W = j.src[job];
    unsigned short* Wt = j.dst[job];
    int x = threadIdx.x & 31, y = threadIdx.x >> 5;
    int n0 = blockIdx.x << 5, k0 = blockIdx.y << 5;
#pragma unroll
    for (int i = 0; i < 32; i += 8) {
        int n = n0 + x;
        t[y + i][x] = (n < N) ? W[(size_t)(k0 + y + i) * N + n] : 0.0f;
    }
    __syncthreads();
#pragma unroll
    for (int i = 0; i < 32; i += 8) {
        int n = n0 + y + i;
        if (n < N) Wt[(size_t)n * K + k0 + x] = f2bf(t[x][y + i]);
    }
}

// ---------------------------------------------------------------- bf16 MFMA GEMM
// C[M,N] = act( A'[M,K] @ W[K,N] + bias ) (+res).  W passed as Wt[N][K] bf16.
// A' = (A-mean)*rstd*g+b per row if LNA. BM=64 fixed, BK=32, 256 thr = 4 waves.
// BIAS2: bias for col>=bsplit comes from bias2[col-bsplit].
template <int BN, int WGM, int WGN, bool LNA, bool BIAS, bool BIAS2, bool GELUF, bool RES, bool OBF16>
__global__ __launch_bounds__(256) void k_mgemm(const float* __restrict__ A, const unsigned short* __restrict__ Bt,
                                               const float* __restrict__ bias, const float* __restrict__ bias2,
                                               int bsplit, const float* __restrict__ res,
                                               const float* __restrict__ stats, const float* __restrict__ lng,
                                               const float* __restrict__ lnb, void* __restrict__ Cout,
                                               int M, int K, int Ncol) {
    constexpr int BM = 64, BK = 32;
    constexpr int WAVE_M = BM / WGM, WAVE_N = BN / WGN;
    constexpr int FM = WAVE_M / 16, FN = WAVE_N / 16;
    constexpr int BUN = BN / 64;  // 16B B-units per thread
    __shared__ __align__(16) short a_lds[4][BM][8];
    __shared__ __align__(16) short b_lds[4][BN][8];
    int tid = threadIdx.x;
    int am0 = blockIdx.y * BM, bn0 = blockIdx.x * BN;
    int ar = tid >> 2, akc = tid & 3;
    const float* Arow = A + (size_t)(am0 + ar) * K + akc * 8;
    float mean = 0.0f, rstd = 0.0f;
    if (LNA) {
        mean = stats[(size_t)(am0 + ar) * 2];
        rstd = stats[(size_t)(am0 + ar) * 2 + 1];
    }
    float4 a0, a1, g0, g1, c0, c1;
    int4 bq[BUN];
    int nsteps = K / BK;

    auto load_tile = [&](int k0) {
        a0 = *(const float4*)(Arow + k0);
        a1 = *(const float4*)(Arow + k0 + 4);
        if (LNA) {
            g0 = *(const float4*)(lng + k0 + akc * 8);
            g1 = *(const float4*)(lng + k0 + akc * 8 + 4);
            c0 = *(const float4*)(lnb + k0 + akc * 8);
            c1 = *(const float4*)(lnb + k0 + akc * 8 + 4);
        }
#pragma unroll
        for (int jj = 0; jj < BUN; jj++) {
            int u = tid + 256 * jj;
            int col = u >> 2, kc = u & 3;
            int gn = bn0 + col;
            if (gn < Ncol)
                bq[jj] = *(const int4*)(Bt + (size_t)gn * K + k0 + kc * 8);
            else
                bq[jj] = make_int4(0, 0, 0, 0);
        }
    };
    auto write_lds = [&]() {
        float v[8] = {a0.x, a0.y, a0.z, a0.w, a1.x, a1.y, a1.z, a1.w};
        if (LNA) {
            float gg[8] = {g0.x, g0.y, g0.z, g0.w, g1.x, g1.y, g1.z, g1.w};
            float bb[8] = {c0.x, c0.y, c0.z, c0.w, c1.x, c1.y, c1.z, c1.w};
#pragma unroll
            for (int e = 0; e < 8; e++) v[e] = (v[e] - mean) * rstd * gg[e] + bb[e];
        }
        bf16x8 pk;
#pragma unroll
        for (int e = 0; e < 8; e++) pk[e] = (short)f2bf(v[e]);
        *(bf16x8*)(&a_lds[akc][ar][0]) = pk;
#pragma unroll
        for (int jj = 0; jj < BUN; jj++) {
            int u = tid + 256 * jj;
            int col = u >> 2, kc = u & 3;
            *(int4*)(&b_lds[kc][col][0]) = bq[jj];
        }
    };
    int lane = tid & 63, wid = tid >> 6;
    int wm = wid / WGN, wn = wid % WGN;
    int fr = lane & 15, fkc = lane >> 4;
    floatx4 acc[FM][FN] = {};

    load_tile(0);
    for (int t = 0; t < nsteps; ++t) {
        if (t) __syncthreads();
        write_lds();
        __syncthreads();
        if (t + 1 < nsteps) load_tile((t + 1) * BK);
        bf16x8 af[FM], bf[FN];
#pragma unroll
        for (int m = 0; m < FM; m++) af[m] = *(const bf16x8*)(&a_lds[fkc][wm * WAVE_M + m * 16 + fr][0]);
#pragma unroll
        for (int n = 0; n < FN; n++) bf[n] = *(const bf16x8*)(&b_lds[fkc][wn * WAVE_N + n * 16 + fr][0]);
#pragma unroll
        for (int m = 0; m < FM; m++)
#pragma unroll
            for (int n = 0; n < FN; n++)
                acc[m][n] = __builtin_amdgcn_mfma_f32_16x16x32_bf16(af[m], bf[n], acc[m][n], 0, 0, 0);
    }
    // epilogue: C/D layout col=lane&15, row=(lane>>4)*4+reg
    int r4 = lane >> 4;
#pragma unroll
    for (int m = 0; m < FM; m++) {
        int row = am0 + wm * WAVE_M + m * 16 + r4 * 4;
#pragma unroll
        for (int n = 0; n < FN; n++) {
            int col = bn0 + wn * WAVE_N + n * 16 + fr;
            if (col < Ncol) {
                float bsc = 0.0f;
                if (BIAS) bsc = (BIAS2 && col >= bsplit) ? bias2[col - bsplit] : bias[col];
#pragma unroll
                for (int r = 0; r < 4; r++) {
                    size_t off = (size_t)(row + r) * Ncol + col;
                    float v = acc[m][n][r] + bsc;
                    if (GELUF) v = gelu_f(v);
                    if (RES) v += res[off];
                    if (OBF16)
                        ((unsigned short*)Cout)[off] = f2bf(v);
                    else
                        ((float*)Cout)[off] = v;
                }
            }
        }
    }
}

// ================================================================ launch
extern "C" void kernel_launch(void* const* d_in, const int* in_sizes, int n_in, void* d_out, int out_size,
                              void* d_ws, size_t ws_size, hipStream_t stream) {
    const float* xin = (const float*)d_in[0];
    const float* src = (const float*)d_in[1];
    const float* cpos = (const float*)d_in[2];
    const float* pos3 = (const float*)d_in[3];
    const float* Wpos = (const float*)d_in[6];
    const float* bpos = (const float*)d_in[7];
    const float* ln1g = (const float*)d_in[8];
    const float* ln1b = (const float*)d_in[9];
    const float* ln2g = (const float*)d_in[10];
    const float* ln2b = (const float*)d_in[11];
    const float* ln3g = (const float*)d_in[12];
    const float* ln3b = (const float*)d_in[13];
    const float* Wq = (const float*)d_in[14];
    const float* Wkv = (const float*)d_in[15];
    const float* Wosa = (const float*)d_in[16];
    const float* bosa = (const float*)d_in[17];
    const float* Wval = (const float*)d_in[18];
    const float* bval = (const float*)d_in[19];
    const float* Woff = (const float*)d_in[20];
    const float* boff = (const float*)d_in[21];
    const float* Waw = (const float*)d_in[22];
    const float* baw = (const float*)d_in[23];
    const float* Woca = (const float*)d_in[24];
    const float* boca = (const float*)d_in[25];
    const float* W1 = (const float*)d_in[26];
    const float* b1 = (const float*)d_in[27];
    const float* W2 = (const float*)d_in[28];
    const float* b2 = (const float*)d_in[29];
    float* x = (float*)d_out;

    float* ws = (float*)d_ws;
    float* sstats = ws;                     // 86016
    float* cpe = sstats + 86016;            // 524288
    float* hbuf = cpe + 524288;             // 524288
    float* hqkv = hbuf + 524288;            // 1572864 (2048*768)
    float* attn_o = hqkv + 1572864;         // 524288
    float* qbuf = attn_o + 524288;          // 524288
    float* offaw = qbuf + 524288;           // 1327104 (2048*648)
    float* cab = offaw + 1327104;           // 524288
    float* ffmid = cab + 524288;            // 1048576
    unsigned short* value = (unsigned short*)(ffmid + 1048576);  // 11010048 shorts
    int* kidx = (int*)(ffmid + 1048576 + 5505024);               // 131072 ints
    unsigned short* wt = (unsigned short*)(kidx + 131072);       // 1642496 shorts

    const size_t WT_STRIDE = 821248;
    // per-depth offsets: Wqkv[768][256] (q rows 0..255, kv rows 256..767), then others
    const size_t O_WQKV = 0, O_WOSA = 196608, O_WVAL = 262144, O_WOFFAW = 327680,
                 O_WOCA = 493568, O_W1 = 559104, O_W2 = 690176;

    TJobs tj;
    for (int d = 0; d < 2; d++) {
        int base = d * 9;
        unsigned short* wd = wt + (size_t)d * WT_STRIDE;
        tj.src[base + 0] = Wq + (size_t)d * 65536;    tj.dst[base + 0] = wd + O_WQKV;          tj.K[base + 0] = 256; tj.N[base + 0] = 256;
        tj.src[base + 1] = Wkv + (size_t)d * 131072;  tj.dst[base + 1] = wd + O_WQKV + 65536;  tj.K[base + 1] = 256; tj.N[base + 1] = 512;
        tj.src[base + 2] = Wosa + (size_t)d * 65536;  tj.dst[base + 2] = wd + O_WOSA;          tj.K[base + 2] = 256; tj.N[base + 2] = 256;
        tj.src[base + 3] = Wval + (size_t)d * 65536;  tj.dst[base + 3] = wd + O_WVAL;          tj.K[base + 3] = 256; tj.N[base + 3] = 256;
        tj.src[base + 4] = Woff + (size_t)d * 110592; tj.dst[base + 4] = wd + O_WOFFAW;        tj.K[base + 4] = 256; tj.N[base + 4] = 432;
        tj.src[base + 5] = Waw + (size_t)d * 55296;   tj.dst[base + 5] = wd + O_WOFFAW + 110592; tj.K[base + 5] = 256; tj.N[base + 5] = 216;
        tj.src[base + 6] = Woca + (size_t)d * 65536;  tj.dst[base + 6] = wd + O_WOCA;          tj.K[base + 6] = 256; tj.N[base + 6] = 256;
        tj.src[base + 7] = W1 + (size_t)d * 131072;   tj.dst[base + 7] = wd + O_W1;            tj.K[base + 7] = 256; tj.N[base + 7] = 512;
        tj.src[base + 8] = W2 + (size_t)d * 131072;   tj.dst[base + 8] = wd + O_W2;            tj.K[base + 8] = 512; tj.N[base + 8] = 256;
    }
    k_tw<<<dim3(16, 16, 18), 256, 0, stream>>>(tj);

    k_copy<<<512, 256, 0, stream>>>((const float4*)xin, (float4*)x, 131072);
    k_rowstats<<<10752, 256, 0, stream>>>(src, sstats);
    k_cpe<<<2048, 256, 0, stream>>>(cpos, Wpos, bpos, cpe);

    for (int i = 0; i < 2; i++) {
        unsigned short* wd = wt + (size_t)i * WT_STRIDE;
        // ---- self-attention (KNN) ----
        k_lnfused<<<512, 256, 0, stream>>>(x, cpe, nullptr, ln1g + i * 256, ln1b + i * 256, hbuf);
        if (i == 0)
            k_knn<16><<<512, 256, 0, stream>>>(pos3, kidx);
        else
            k_knn<64><<<512, 256, 0, stream>>>(pos3, kidx);
        k_mgemm<64, 2, 2, false, false, false, false, false, false><<<dim3(12, 32), 256, 0, stream>>>(
            hbuf, wd + O_WQKV, nullptr, nullptr, 0, nullptr, nullptr, nullptr, nullptr, hqkv, 2048, 256, 768);
        if (i == 0)
            k_attn<16><<<2048, 256, 0, stream>>>(hqkv, kidx, attn_o);
        else
            k_attn<64><<<2048, 256, 0, stream>>>(hqkv, kidx, attn_o);
        k_mgemm<64, 2, 2, false, true, false, false, true, false><<<dim3(4, 32), 256, 0, stream>>>(
            attn_o, wd + O_WOSA, bosa + i * 256, nullptr, 0, x, nullptr, nullptr, nullptr, x, 2048, 256, 256);

        // ---- ms-deform cross-attention ----
        k_lnfused<<<512, 256, 0, stream>>>(x, nullptr, cpe, ln2g + i * 256, ln2b + i * 256, qbuf);
        k_mgemm<256, 1, 4, true, true, false, false, false, true><<<dim3(1, 672), 256, 0, stream>>>(
            src, wd + O_WVAL, bval + i * 256, nullptr, 0, nullptr, sstats, ln2g + i * 256, ln2b + i * 256, value, 43008, 256, 256);
        k_mgemm<64, 2, 2, false, true, true, false, false, false><<<dim3(11, 32), 256, 0, stream>>>(
            qbuf, wd + O_WOFFAW, boff + i * 432, baw + i * 216, 432, nullptr, nullptr, nullptr, nullptr, offaw, 2048, 256, 648);
        k_msdeform<<<2048, 256, 0, stream>>>(offaw, cpos, value, cab);
        k_mgemm<64, 2, 2, false, true, false, false, true, false><<<dim3(4, 32), 256, 0, stream>>>(
            cab, wd + O_WOCA, boca + i * 256, nullptr, 0, x, nullptr, nullptr, nullptr, x, 2048, 256, 256);

        // ---- FFN ----
        k_lnfused<<<512, 256, 0, stream>>>(x, nullptr, nullptr, ln3g + i * 256, ln3b + i * 256, hbuf);
        k_mgemm<64, 2, 2, false, true, false, true, false, false><<<dim3(8, 32), 256, 0, stream>>>(
            hbuf, wd + O_W1, b1 + i * 512, nullptr, 0, nullptr, nullptr, nullptr, nullptr, ffmid, 2048, 256, 512);
        k_mgemm<64, 2, 2, false, true, false, false, true, false><<<dim3(4, 32), 256, 0, stream>>>(
            ffmid, wd + O_W2, b2 + i * 256, nullptr, 0, x, nullptr, nullptr, nullptr, x, 2048, 512, 256);
    }
}

// Round 4
// 339.232 us; speedup vs baseline: 2.2527x; 1.1196x over previous
//
#include <hip/hip_runtime.h>
#include <math.h>

// Problem constants (hard-coded from reference)
// B=2, N=1024, C=256, HEADS=8, DH=32, INNER=256, L=3, P=9, FF=512, DEPTH=2
// LEN = 128*128 + 64*64 + 32*32 = 21504, level starts {0, 16384, 20480}

#define DEV __device__ __forceinline__

typedef __attribute__((ext_vector_type(8))) short bf16x8;
typedef __attribute__((ext_vector_type(4))) float floatx4;

DEV float gelu_f(float v) { return 0.5f * v * (1.0f + erff(v * 0.7071067811865475f)); }

DEV unsigned short f2bf(float f) {  // RTNE f32 -> bf16
    unsigned u = __float_as_uint(f);
    return (unsigned short)((u + 0x7fffu + ((u >> 16) & 1u)) >> 16);
}
DEV float bf2f(unsigned short s) { return __uint_as_float((unsigned)s << 16); }

// ---------------------------------------------------------------- copy x -> out
__global__ __launch_bounds__(256) void k_copy(const float4* __restrict__ a, float4* __restrict__ o, int n4) {
    int i = blockIdx.x * 256 + threadIdx.x;
    if (i < n4) o[i] = a[i];
}

// ------------------------------------------------- row stats (mean, rstd) of src
__global__ __launch_bounds__(256) void k_rowstats(const float* __restrict__ x, float* __restrict__ st) {
    int wid = threadIdx.x >> 6, lane = threadIdx.x & 63;
    size_t row = (size_t)blockIdx.x * 4 + wid;
    float4 v = ((const float4*)(x + row * 256))[lane];
    float s = (v.x + v.y) + (v.z + v.w);
#pragma unroll
    for (int o = 32; o; o >>= 1) s += __shfl_xor(s, o);
    float mean = s * (1.0f / 256.0f);
    float dx = v.x - mean, dy = v.y - mean, dz = v.z - mean, dw = v.w - mean;
    float q = (dx * dx + dy * dy) + (dz * dz + dw * dw);
#pragma unroll
    for (int o = 32; o; o >>= 1) q += __shfl_xor(q, o);
    if (lane == 0) {
        st[row * 2] = mean;
        st[row * 2 + 1] = 1.0f / sqrtf(q * (1.0f / 256.0f) + 1e-5f);
    }
}

// ---------------------------------------------------------------- cpe
__global__ __launch_bounds__(256) void k_cpe(const float* __restrict__ cpos, const float* __restrict__ Wp,
                                             const float* __restrict__ bp, float* __restrict__ cpe) {
    int bn = blockIdx.x, c = threadIdx.x;
    float px = cpos[(size_t)bn * 6 + 0], py = cpos[(size_t)bn * 6 + 1];
    cpe[(size_t)bn * 256 + c] = px * Wp[c] + py * Wp[256 + c] + bp[c];
}

// ------------------------------------------- out = LN(x [+pre]) * g + b [+post]
__global__ __launch_bounds__(256) void k_lnfused(const float* __restrict__ x, const float* pre, const float* post,
                                                 const float* __restrict__ g, const float* __restrict__ b,
                                                 float* __restrict__ out) {
    int wid = threadIdx.x >> 6, lane = threadIdx.x & 63;
    size_t row = (size_t)blockIdx.x * 4 + wid;
    float4 v = ((const float4*)(x + row * 256))[lane];
    if (pre) {
        float4 p = ((const float4*)(pre + row * 256))[lane];
        v.x += p.x; v.y += p.y; v.z += p.z; v.w += p.w;
    }
    float s = (v.x + v.y) + (v.z + v.w);
#pragma unroll
    for (int o = 32; o; o >>= 1) s += __shfl_xor(s, o);
    float mean = s * (1.0f / 256.0f);
    float dx = v.x - mean, dy = v.y - mean, dz = v.z - mean, dw = v.w - mean;
    float q = (dx * dx + dy * dy) + (dz * dz + dw * dw);
#pragma unroll
    for (int o = 32; o; o >>= 1) q += __shfl_xor(q, o);
    float rstd = 1.0f / sqrtf(q * (1.0f / 256.0f) + 1e-5f);
    float4 gg = ((const float4*)g)[lane], bb = ((const float4*)b)[lane];
    float4 o4;
    o4.x = dx * rstd * gg.x + bb.x;
    o4.y = dy * rstd * gg.y + bb.y;
    o4.z = dz * rstd * gg.z + bb.z;
    o4.w = dw * rstd * gg.w + bb.w;
    if (post) {
        float4 p = ((const float4*)(post + row * 256))[lane];
        o4.x += p.x; o4.y += p.y; o4.z += p.z; o4.w += p.w;
    }
    ((float4*)(out + row * 256))[lane] = o4;
}

// ---------------------------------------------------------------- KNN (both k=16 and k=64 in one pass)
// One wave per query. Distances -> order-preserving u32. Wave-uniform binary
// search for the K-th smallest via ballot+popcount (scalar-side counting),
// then ballot-prefix compaction. Ties at threshold taken by ascending index
// (matches jax.lax.top_k tie-break). Output order is arbitrary: downstream
// attention is permutation-invariant over the neighbor set.
__global__ __launch_bounds__(256) void k_knn2(const float* __restrict__ pos, int* __restrict__ k16,
                                              int* __restrict__ k64) {
    __shared__ float sp[3072];
    int b = blockIdx.x >> 8;
    int n0 = (blockIdx.x & 255) * 4;
    for (int t = threadIdx.x; t < 3072; t += 256) sp[t] = pos[(size_t)b * 3072 + t];
    __syncthreads();
    int wid = threadIdx.x >> 6, lane = threadIdx.x & 63;
    int n = n0 + wid;
    float qx = sp[n * 3], qy = sp[n * 3 + 1], qz = sp[n * 3 + 2];
    float sqn = (qx * qx + qy * qy) + qz * qz;
    unsigned du[16];
#pragma unroll
    for (int t = 0; t < 16; t++) {
        int m = t * 64 + lane;
        float mx = sp[m * 3], my = sp[m * 3 + 1], mz = sp[m * 3 + 2];
        float sqm = (mx * mx + my * my) + mz * mz;
        float dt = (qx * mx + qy * my) + qz * mz;
        float d2 = (sqn + sqm) - 2.0f * dt;
        unsigned u = __float_as_uint(d2);
        du[t] = (u & 0x80000000u) ? ~u : (u | 0x80000000u);  // order-preserving
    }
    unsigned long long lmask = (1ull << lane) - 1ull;

    auto cnt_le = [&](unsigned p) {
        int c = 0;
#pragma unroll
        for (int t = 0; t < 16; t++) c += __popcll(__ballot(du[t] <= p));
        return c;
    };
    auto find_T = [&](int K) {  // smallest T with cnt_le(T) >= K  (wave-uniform)
        unsigned lo = 0u, hi = 0xFFFFFFFFu;
        while (lo < hi) {
            unsigned mid = lo + ((hi - lo) >> 1);
            if (cnt_le(mid) >= K) hi = mid; else lo = mid + 1;
        }
        return hi;
    };
    auto emit = [&](int K, unsigned T, int* out) {
        int base = 0;
#pragma unroll
        for (int t = 0; t < 16; t++) {
            bool lt = du[t] < T;
            unsigned long long mk = __ballot(lt);
            if (lt) out[base + __popcll(mk & lmask)] = t * 64 + lane;
            base += __popcll(mk);
        }
        int need = K - base, eb = 0;
#pragma unroll
        for (int t = 0; t < 16; t++) {
            bool eq = du[t] == T;
            unsigned long long mk = __ballot(eq);
            if (eq) {
                int r = eb + __popcll(mk & lmask);
                if (r < need) out[base + r] = t * 64 + lane;
            }
            eb += __popcll(mk);
        }
    };
    unsigned T16 = find_T(16);
    emit(16, T16, k16 + ((size_t)b * 1024 + n) * 16);
    unsigned T64 = find_T(64);
    emit(64, T64, k64 + ((size_t)b * 1024 + n) * 64);
}

// ---------------------------------------------------------------- knn attention
// hqkv[row][768]: q at 0, k at 256, v at 512.
template <int KK>
__global__ __launch_bounds__(256) void k_attn(const float* __restrict__ hqkv, const int* __restrict__ kidx,
                                              float* __restrict__ out) {
    int bn = blockIdx.x;
    int b = bn >> 10;
    int tid = threadIdx.x;
    __shared__ float sq[256];
    __shared__ float sa[8][KK];
    __shared__ int si[KK];
    if (tid < KK) si[tid] = kidx[(size_t)bn * KK + tid];
    sq[tid] = hqkv[(size_t)bn * 768 + tid] * 0.17677669529663689f;  // DH^-0.5
    __syncthreads();
    const float* kvb = hqkv + (size_t)b * 1024 * 768;
#pragma unroll
    for (int pair = tid; pair < 8 * KK; pair += 256) {
        int s = pair & (KK - 1);
        int h = pair / KK;
        const float4* kr = (const float4*)(kvb + (size_t)si[s] * 768 + 256 + h * 32);
        const float4* q4 = (const float4*)&sq[h * 32];
        float a0 = 0.f, a1 = 0.f, a2 = 0.f, a3 = 0.f;
#pragma unroll
        for (int e = 0; e < 8; e++) {
            float4 kv = kr[e];
            float4 qv = q4[e];
            a0 = fmaf(kv.x, qv.x, a0);
            a1 = fmaf(kv.y, qv.y, a1);
            a2 = fmaf(kv.z, qv.z, a2);
            a3 = fmaf(kv.w, qv.w, a3);
        }
        sa[h][s] = (a0 + a1) + (a2 + a3);
    }
    __syncthreads();
    int h = tid >> 5, d = tid & 31;
    float mx = -1e30f;
    for (int s = d; s < KK; s += 32) mx = fmaxf(mx, sa[h][s]);
#pragma unroll
    for (int o = 16; o; o >>= 1) mx = fmaxf(mx, __shfl_xor(mx, o, 32));
    float sum = 0.0f;
    for (int s = d; s < KK; s += 32) {
        float e = __expf(sa[h][s] - mx);
        sa[h][s] = e;
        sum += e;
    }
#pragma unroll
    for (int o = 16; o; o >>= 1) sum += __shfl_xor(sum, o, 32);
    float inv = 1.0f / sum;
    __syncthreads();
    float acc = 0.0f;
    for (int s = 0; s < KK; s++) {
        float vv = kvb[(size_t)si[s] * 768 + 512 + tid];
        acc += sa[h][s] * vv;
    }
    out[(size_t)bn * 256 + tid] = acc * inv;
}

// ------------------------------------------------- ms-deform sampling (value bf16; offaw concat [648])
__global__ __launch_bounds__(256) void k_msdeform(const float* __restrict__ offaw, const float* __restrict__ cpos,
                                                  const unsigned short* __restrict__ value, float* __restrict__ out) {
    int bn = blockIdx.x;
    int b = bn >> 10;
    int tid = threadIdx.x;
    int h = tid >> 5;
    __shared__ float aw[216];
    if (tid < 216) aw[tid] = offaw[(size_t)bn * 648 + 432 + tid];
    __syncthreads();
    if (tid < 8) {
        float mx = -1e30f;
        for (int p = 0; p < 27; p++) mx = fmaxf(mx, aw[tid * 27 + p]);
        float s = 0.0f;
        for (int p = 0; p < 27; p++) {
            float e = __expf(aw[tid * 27 + p] - mx);
            aw[tid * 27 + p] = e;
            s += e;
        }
        float inv = 1.0f / s;
        for (int p = 0; p < 27; p++) aw[tid * 27 + p] *= inv;
    }
    __syncthreads();
    const float* offr = offaw + (size_t)bn * 648 + h * 54;
    const unsigned short* vb = value + (size_t)b * 21504 * 256;
    const int dims[3] = {128, 64, 32};
    const int starts[3] = {0, 16384, 20480};
    float acc = 0.0f;
#pragma unroll
    for (int l = 0; l < 3; l++) {
        int Wl = dims[l];
        int st = starts[l];
        float rx = cpos[(size_t)bn * 6 + l * 2], ry = cpos[(size_t)bn * 6 + l * 2 + 1];
        float rw = 1.0f / (float)Wl;
#pragma unroll
        for (int p = 0; p < 9; p++) {
            float ox = offr[l * 18 + p * 2], oy = offr[l * 18 + p * 2 + 1];
            float xf = (rx + ox * rw) * (float)Wl - 0.5f;
            float yf = (ry + oy * rw) * (float)Wl - 0.5f;
            float x0 = floorf(xf), y0 = floorf(yf);
            float wgt = aw[h * 27 + l * 9 + p];
#pragma unroll
            for (int cy = 0; cy < 2; cy++) {
#pragma unroll
                for (int cx = 0; cx < 2; cx++) {
                    float ix = x0 + cx, iy = y0 + cy;
                    float w = (1.0f - fabsf(xf - ix)) * (1.0f - fabsf(yf - iy));
                    if (ix >= 0.0f && ix <= (float)(Wl - 1) && iy >= 0.0f && iy <= (float)(Wl - 1) && w != 0.0f) {
                        int flat = st + (int)iy * Wl + (int)ix;
                        acc += (w * wgt) * bf2f(vb[(size_t)flat * 256 + tid]);
                    }
                }
            }
        }
    }
    out[(size_t)bn * 256 + tid] = acc;
}

// ------------------------------------------- weight transpose+convert: W[K][N] f32 -> Wt[N][K] bf16
struct TJobs {
    const float* src[18];
    unsigned short* dst[18];
    int K[18];
    int N[18];
};
__global__ __launch_bounds__(256) void k_tw(TJobs j) {
    int job = blockIdx.z;
    int K = j.K[job], N = j.N[job];
    int nt = (N + 31) >> 5, kt = K >> 5;
    if ((int)blockIdx.x >= nt || (int)blockIdx.y >= kt) return;
    __shared__ float t[32][33];
    const float* W = j.src[job];
    unsigned short* Wt = j.dst[job];
    int x = threadIdx.x & 31, y = threadIdx.x >> 5;
    int n0 = blockIdx.x << 5, k0 = blockIdx.y << 5;
#pragma unroll
    for (int i = 0; i < 32; i += 8) {
        int n = n0 + x;
        t[y + i][x] = (n < N) ? W[(size_t)(k0 + y + i) * N + n] : 0.0f;
    }
    __syncthreads();
#pragma unroll
    for (int i = 0; i < 32; i += 8) {
        int n = n0 + y + i;
        if (n < N) Wt[(size_t)n * K + k0 + x] = f2bf(t[x][y + i]);
    }
}

// ---------------------------------------------------------------- bf16 MFMA GEMM
// C[M,N] = act( A'[M,K] @ W[K,N] + bias ) (+res).  W passed as Wt[N][K] bf16.
// A' = (A-mean)*rstd*g+b per row if LNA. BM=64 fixed, BK=32, 256 thr = 4 waves.
// BIAS2: bias for col>=bsplit comes from bias2[col-bsplit].
template <int BN, int WGM, int WGN, bool LNA, bool BIAS, bool BIAS2, bool GELUF, bool RES, bool OBF16>
__global__ __launch_bounds__(256) void k_mgemm(const float* __restrict__ A, const unsigned short* __restrict__ Bt,
                                               const float* __restrict__ bias, const float* __restrict__ bias2,
                                               int bsplit, const float* __restrict__ res,
                                               const float* __restrict__ stats, const float* __restrict__ lng,
                                               const float* __restrict__ lnb, void* __restrict__ Cout,
                                               int M, int K, int Ncol) {
    constexpr int BM = 64, BK = 32;
    constexpr int WAVE_M = BM / WGM, WAVE_N = BN / WGN;
    constexpr int FM = WAVE_M / 16, FN = WAVE_N / 16;
    constexpr int BUN = BN / 64;  // 16B B-units per thread
    __shared__ __align__(16) short a_lds[4][BM][8];
    __shared__ __align__(16) short b_lds[4][BN][8];
    int tid = threadIdx.x;
    int am0 = blockIdx.y * BM, bn0 = blockIdx.x * BN;
    int ar = tid >> 2, akc = tid & 3;
    const float* Arow = A + (size_t)(am0 + ar) * K + akc * 8;
    float mean = 0.0f, rstd = 0.0f;
    if (LNA) {
        mean = stats[(size_t)(am0 + ar) * 2];
        rstd = stats[(size_t)(am0 + ar) * 2 + 1];
    }
    float4 a0, a1, g0, g1, c0, c1;
    int4 bq[BUN];
    int nsteps = K / BK;

    auto load_tile = [&](int k0) {
        a0 = *(const float4*)(Arow + k0);
        a1 = *(const float4*)(Arow + k0 + 4);
        if (LNA) {
            g0 = *(const float4*)(lng + k0 + akc * 8);
            g1 = *(const float4*)(lng + k0 + akc * 8 + 4);
            c0 = *(const float4*)(lnb + k0 + akc * 8);
            c1 = *(const float4*)(lnb + k0 + akc * 8 + 4);
        }
#pragma unroll
        for (int jj = 0; jj < BUN; jj++) {
            int u = tid + 256 * jj;
            int col = u >> 2, kc = u & 3;
            int gn = bn0 + col;
            if (gn < Ncol)
                bq[jj] = *(const int4*)(Bt + (size_t)gn * K + k0 + kc * 8);
            else
                bq[jj] = make_int4(0, 0, 0, 0);
        }
    };
    auto write_lds = [&]() {
        float v[8] = {a0.x, a0.y, a0.z, a0.w, a1.x, a1.y, a1.z, a1.w};
        if (LNA) {
            float gg[8] = {g0.x, g0.y, g0.z, g0.w, g1.x, g1.y, g1.z, g1.w};
            float bb[8] = {c0.x, c0.y, c0.z, c0.w, c1.x, c1.y, c1.z, c1.w};
#pragma unroll
            for (int e = 0; e < 8; e++) v[e] = (v[e] - mean) * rstd * gg[e] + bb[e];
        }
        bf16x8 pk;
#pragma unroll
        for (int e = 0; e < 8; e++) pk[e] = (short)f2bf(v[e]);
        *(bf16x8*)(&a_lds[akc][ar][0]) = pk;
#pragma unroll
        for (int jj = 0; jj < BUN; jj++) {
            int u = tid + 256 * jj;
            int col = u >> 2, kc = u & 3;
            *(int4*)(&b_lds[kc][col][0]) = bq[jj];
        }
    };
    int lane = tid & 63, wid = tid >> 6;
    int wm = wid / WGN, wn = wid % WGN;
    int fr = lane & 15, fkc = lane >> 4;
    floatx4 acc[FM][FN] = {};

    load_tile(0);
    for (int t = 0; t < nsteps; ++t) {
        if (t) __syncthreads();
        write_lds();
        __syncthreads();
        if (t + 1 < nsteps) load_tile((t + 1) * BK);
        bf16x8 af[FM], bf[FN];
#pragma unroll
        for (int m = 0; m < FM; m++) af[m] = *(const bf16x8*)(&a_lds[fkc][wm * WAVE_M + m * 16 + fr][0]);
#pragma unroll
        for (int n = 0; n < FN; n++) bf[n] = *(const bf16x8*)(&b_lds[fkc][wn * WAVE_N + n * 16 + fr][0]);
#pragma unroll
        for (int m = 0; m < FM; m++)
#pragma unroll
            for (int n = 0; n < FN; n++)
                acc[m][n] = __builtin_amdgcn_mfma_f32_16x16x32_bf16(af[m], bf[n], acc[m][n], 0, 0, 0);
    }
    // epilogue: C/D layout col=lane&15, row=(lane>>4)*4+reg
    int r4 = lane >> 4;
#pragma unroll
    for (int m = 0; m < FM; m++) {
        int row = am0 + wm * WAVE_M + m * 16 + r4 * 4;
#pragma unroll
        for (int n = 0; n < FN; n++) {
            int col = bn0 + wn * WAVE_N + n * 16 + fr;
            if (col < Ncol) {
                float bsc = 0.0f;
                if (BIAS) bsc = (BIAS2 && col >= bsplit) ? bias2[col - bsplit] : bias[col];
#pragma unroll
                for (int r = 0; r < 4; r++) {
                    size_t off = (size_t)(row + r) * Ncol + col;
                    float v = acc[m][n][r] + bsc;
                    if (GELUF) v = gelu_f(v);
                    if (RES) v += res[off];
                    if (OBF16)
                        ((unsigned short*)Cout)[off] = f2bf(v);
                    else
                        ((float*)Cout)[off] = v;
                }
            }
        }
    }
}

// ================================================================ launch
extern "C" void kernel_launch(void* const* d_in, const int* in_sizes, int n_in, void* d_out, int out_size,
                              void* d_ws, size_t ws_size, hipStream_t stream) {
    const float* xin = (const float*)d_in[0];
    const float* src = (const float*)d_in[1];
    const float* cpos = (const float*)d_in[2];
    const float* pos3 = (const float*)d_in[3];
    const float* Wpos = (const float*)d_in[6];
    const float* bpos = (const float*)d_in[7];
    const float* ln1g = (const float*)d_in[8];
    const float* ln1b = (const float*)d_in[9];
    const float* ln2g = (const float*)d_in[10];
    const float* ln2b = (const float*)d_in[11];
    const float* ln3g = (const float*)d_in[12];
    const float* ln3b = (const float*)d_in[13];
    const float* Wq = (const float*)d_in[14];
    const float* Wkv = (const float*)d_in[15];
    const float* Wosa = (const float*)d_in[16];
    const float* bosa = (const float*)d_in[17];
    const float* Wval = (const float*)d_in[18];
    const float* bval = (const float*)d_in[19];
    const float* Woff = (const float*)d_in[20];
    const float* boff = (const float*)d_in[21];
    const float* Waw = (const float*)d_in[22];
    const float* baw = (const float*)d_in[23];
    const float* Woca = (const float*)d_in[24];
    const float* boca = (const float*)d_in[25];
    const float* W1 = (const float*)d_in[26];
    const float* b1 = (const float*)d_in[27];
    const float* W2 = (const float*)d_in[28];
    const float* b2 = (const float*)d_in[29];
    float* x = (float*)d_out;

    float* ws = (float*)d_ws;
    float* sstats = ws;                     // 86016
    float* cpe = sstats + 86016;            // 524288
    float* hbuf = cpe + 524288;             // 524288
    float* hqkv = hbuf + 524288;            // 1572864 (2048*768)
    float* attn_o = hqkv + 1572864;         // 524288
    float* qbuf = attn_o + 524288;          // 524288
    float* offaw = qbuf + 524288;           // 1327104 (2048*648)
    float* cab = offaw + 1327104;           // 524288
    float* ffmid = cab + 524288;            // 1048576
    unsigned short* value = (unsigned short*)(ffmid + 1048576);  // 11010048 shorts
    int* kidx16 = (int*)(ffmid + 1048576 + 5505024);             // 32768 ints
    int* kidx64 = kidx16 + 32768;                                // 131072 ints
    unsigned short* wt = (unsigned short*)(kidx64 + 131072);     // 1642496 shorts

    const size_t WT_STRIDE = 821248;
    // per-depth offsets: Wqkv[768][256] (q rows 0..255, kv rows 256..767), then others
    const size_t O_WQKV = 0, O_WOSA = 196608, O_WVAL = 262144, O_WOFFAW = 327680,
                 O_WOCA = 493568, O_W1 = 559104, O_W2 = 690176;

    TJobs tj;
    for (int d = 0; d < 2; d++) {
        int base = d * 9;
        unsigned short* wd = wt + (size_t)d * WT_STRIDE;
        tj.src[base + 0] = Wq + (size_t)d * 65536;    tj.dst[base + 0] = wd + O_WQKV;          tj.K[base + 0] = 256; tj.N[base + 0] = 256;
        tj.src[base + 1] = Wkv + (size_t)d * 131072;  tj.dst[base + 1] = wd + O_WQKV + 65536;  tj.K[base + 1] = 256; tj.N[base + 1] = 512;
        tj.src[base + 2] = Wosa + (size_t)d * 65536;  tj.dst[base + 2] = wd + O_WOSA;          tj.K[base + 2] = 256; tj.N[base + 2] = 256;
        tj.src[base + 3] = Wval + (size_t)d * 65536;  tj.dst[base + 3] = wd + O_WVAL;          tj.K[base + 3] = 256; tj.N[base + 3] = 256;
        tj.src[base + 4] = Woff + (size_t)d * 110592; tj.dst[base + 4] = wd + O_WOFFAW;        tj.K[base + 4] = 256; tj.N[base + 4] = 432;
        tj.src[base + 5] = Waw + (size_t)d * 55296;   tj.dst[base + 5] = wd + O_WOFFAW + 110592; tj.K[base + 5] = 256; tj.N[base + 5] = 216;
        tj.src[base + 6] = Woca + (size_t)d * 65536;  tj.dst[base + 6] = wd + O_WOCA;          tj.K[base + 6] = 256; tj.N[base + 6] = 256;
        tj.src[base + 7] = W1 + (size_t)d * 131072;   tj.dst[base + 7] = wd + O_W1;            tj.K[base + 7] = 256; tj.N[base + 7] = 512;
        tj.src[base + 8] = W2 + (size_t)d * 131072;   tj.dst[base + 8] = wd + O_W2;            tj.K[base + 8] = 512; tj.N[base + 8] = 256;
    }
    k_tw<<<dim3(16, 16, 18), 256, 0, stream>>>(tj);

    k_copy<<<512, 256, 0, stream>>>((const float4*)xin, (float4*)x, 131072);
    k_rowstats<<<10752, 256, 0, stream>>>(src, sstats);
    k_cpe<<<2048, 256, 0, stream>>>(cpos, Wpos, bpos, cpe);
    k_knn2<<<512, 256, 0, stream>>>(pos3, kidx16, kidx64);

    for (int i = 0; i < 2; i++) {
        unsigned short* wd = wt + (size_t)i * WT_STRIDE;
        // ---- self-attention (KNN) ----
        k_lnfused<<<512, 256, 0, stream>>>(x, cpe, nullptr, ln1g + i * 256, ln1b + i * 256, hbuf);
        k_mgemm<64, 2, 2, false, false, false, false, false, false><<<dim3(12, 32), 256, 0, stream>>>(
            hbuf, wd + O_WQKV, nullptr, nullptr, 0, nullptr, nullptr, nullptr, nullptr, hqkv, 2048, 256, 768);
        if (i == 0)
            k_attn<16><<<2048, 256, 0, stream>>>(hqkv, kidx16, attn_o);
        else
            k_attn<64><<<2048, 256, 0, stream>>>(hqkv, kidx64, attn_o);
        k_mgemm<64, 2, 2, false, true, false, false, true, false><<<dim3(4, 32), 256, 0, stream>>>(
            attn_o, wd + O_WOSA, bosa + i * 256, nullptr, 0, x, nullptr, nullptr, nullptr, x, 2048, 256, 256);

        // ---- ms-deform cross-attention ----
        k_lnfused<<<512, 256, 0, stream>>>(x, nullptr, cpe, ln2g + i * 256, ln2b + i * 256, qbuf);
        k_mgemm<256, 1, 4, true, true, false, false, false, true><<<dim3(1, 672), 256, 0, stream>>>(
            src, wd + O_WVAL, bval + i * 256, nullptr, 0, nullptr, sstats, ln2g + i * 256, ln2b + i * 256, value, 43008, 256, 256);
        k_mgemm<64, 2, 2, false, true, true, false, false, false><<<dim3(11, 32), 256, 0, stream>>>(
            qbuf, wd + O_WOFFAW, boff + i * 432, baw + i * 216, 432, nullptr, nullptr, nullptr, nullptr, offaw, 2048, 256, 648);
        k_msdeform<<<2048, 256, 0, stream>>>(offaw, cpos, value, cab);
        k_mgemm<64, 2, 2, false, true, false, false, true, false><<<dim3(4, 32), 256, 0, stream>>>(
            cab, wd + O_WOCA, boca + i * 256, nullptr, 0, x, nullptr, nullptr, nullptr, x, 2048, 256, 256);

        // ---- FFN ----
        k_lnfused<<<512, 256, 0, stream>>>(x, nullptr, nullptr, ln3g + i * 256, ln3b + i * 256, hbuf);
        k_mgemm<64, 2, 2, false, true, false, true, false, false><<<dim3(8, 32), 256, 0, stream>>>(
            hbuf, wd + O_W1, b1 + i * 512, nullptr, 0, nullptr, nullptr, nullptr, nullptr, ffmid, 2048, 256, 512);
        k_mgemm<64, 2, 2, false, true, false, false, true, false><<<dim3(4, 32), 256, 0, stream>>>(
            ffmid, wd + O_W2, b2 + i * 256, nullptr, 0, x, nullptr, nullptr, nullptr, x, 2048, 512, 256);
    }
}

// Round 5
// 271.532 us; speedup vs baseline: 2.8144x; 1.2493x over previous
//
#include <hip/hip_runtime.h>
#include <math.h>

// Problem constants (hard-coded from reference)
// B=2, N=1024, C=256, HEADS=8, DH=32, INNER=256, L=3, P=9, FF=512, DEPTH=2
// LEN = 128*128 + 64*64 + 32*32 = 21504, level starts {0, 16384, 20480}

#define DEV __device__ __forceinline__

typedef __attribute__((ext_vector_type(8))) short bf16x8;
typedef __attribute__((ext_vector_type(4))) float floatx4;

DEV float gelu_f(float v) { return 0.5f * v * (1.0f + erff(v * 0.7071067811865475f)); }

DEV unsigned short f2bf(float f) {  // RTNE f32 -> bf16
    unsigned u = __float_as_uint(f);
    return (unsigned short)((u + 0x7fffu + ((u >> 16) & 1u)) >> 16);
}
DEV float bf2f(unsigned short s) { return __uint_as_float((unsigned)s << 16); }

// ---------------------------------------------------------------- copy x -> out
__global__ __launch_bounds__(256) void k_copy(const float4* __restrict__ a, float4* __restrict__ o, int n4) {
    int i = blockIdx.x * 256 + threadIdx.x;
    if (i < n4) o[i] = a[i];
}

// ------------------------------------------------- row stats (mean, rstd) of src
__global__ __launch_bounds__(256) void k_rowstats(const float* __restrict__ x, float* __restrict__ st) {
    int wid = threadIdx.x >> 6, lane = threadIdx.x & 63;
    size_t row = (size_t)blockIdx.x * 4 + wid;
    float4 v = ((const float4*)(x + row * 256))[lane];
    float s = (v.x + v.y) + (v.z + v.w);
#pragma unroll
    for (int o = 32; o; o >>= 1) s += __shfl_xor(s, o);
    float mean = s * (1.0f / 256.0f);
    float dx = v.x - mean, dy = v.y - mean, dz = v.z - mean, dw = v.w - mean;
    float q = (dx * dx + dy * dy) + (dz * dz + dw * dw);
#pragma unroll
    for (int o = 32; o; o >>= 1) q += __shfl_xor(q, o);
    if (lane == 0) {
        st[row * 2] = mean;
        st[row * 2 + 1] = 1.0f / sqrtf(q * (1.0f / 256.0f) + 1e-5f);
    }
}

// ---------------------------------------------------------------- cpe
__global__ __launch_bounds__(256) void k_cpe(const float* __restrict__ cpos, const float* __restrict__ Wp,
                                             const float* __restrict__ bp, float* __restrict__ cpe) {
    int bn = blockIdx.x, c = threadIdx.x;
    float px = cpos[(size_t)bn * 6 + 0], py = cpos[(size_t)bn * 6 + 1];
    cpe[(size_t)bn * 256 + c] = px * Wp[c] + py * Wp[256 + c] + bp[c];
}

// ------------------------------------------- out = LN(x [+pre]) * g + b [+post]
__global__ __launch_bounds__(256) void k_lnfused(const float* __restrict__ x, const float* pre, const float* post,
                                                 const float* __restrict__ g, const float* __restrict__ b,
                                                 float* __restrict__ out) {
    int wid = threadIdx.x >> 6, lane = threadIdx.x & 63;
    size_t row = (size_t)blockIdx.x * 4 + wid;
    float4 v = ((const float4*)(x + row * 256))[lane];
    if (pre) {
        float4 p = ((const float4*)(pre + row * 256))[lane];
        v.x += p.x; v.y += p.y; v.z += p.z; v.w += p.w;
    }
    float s = (v.x + v.y) + (v.z + v.w);
#pragma unroll
    for (int o = 32; o; o >>= 1) s += __shfl_xor(s, o);
    float mean = s * (1.0f / 256.0f);
    float dx = v.x - mean, dy = v.y - mean, dz = v.z - mean, dw = v.w - mean;
    float q = (dx * dx + dy * dy) + (dz * dz + dw * dw);
#pragma unroll
    for (int o = 32; o; o >>= 1) q += __shfl_xor(q, o);
    float rstd = 1.0f / sqrtf(q * (1.0f / 256.0f) + 1e-5f);
    float4 gg = ((const float4*)g)[lane], bb = ((const float4*)b)[lane];
    float4 o4;
    o4.x = dx * rstd * gg.x + bb.x;
    o4.y = dy * rstd * gg.y + bb.y;
    o4.z = dz * rstd * gg.z + bb.z;
    o4.w = dw * rstd * gg.w + bb.w;
    if (post) {
        float4 p = ((const float4*)(post + row * 256))[lane];
        o4.x += p.x; o4.y += p.y; o4.z += p.z; o4.w += p.w;
    }
    ((float4*)(out + row * 256))[lane] = o4;
}

// ---------------------------------------------------------------- KNN (both k=16 and k=64 in one pass)
__global__ __launch_bounds__(256) void k_knn2(const float* __restrict__ pos, int* __restrict__ k16,
                                              int* __restrict__ k64) {
    __shared__ float sp[3072];
    int b = blockIdx.x >> 8;
    int n0 = (blockIdx.x & 255) * 4;
    for (int t = threadIdx.x; t < 3072; t += 256) sp[t] = pos[(size_t)b * 3072 + t];
    __syncthreads();
    int wid = threadIdx.x >> 6, lane = threadIdx.x & 63;
    int n = n0 + wid;
    float qx = sp[n * 3], qy = sp[n * 3 + 1], qz = sp[n * 3 + 2];
    float sqn = (qx * qx + qy * qy) + qz * qz;
    unsigned du[16];
#pragma unroll
    for (int t = 0; t < 16; t++) {
        int m = t * 64 + lane;
        float mx = sp[m * 3], my = sp[m * 3 + 1], mz = sp[m * 3 + 2];
        float sqm = (mx * mx + my * my) + mz * mz;
        float dt = (qx * mx + qy * my) + qz * mz;
        float d2 = (sqn + sqm) - 2.0f * dt;
        unsigned u = __float_as_uint(d2);
        du[t] = (u & 0x80000000u) ? ~u : (u | 0x80000000u);  // order-preserving
    }
    unsigned long long lmask = (1ull << lane) - 1ull;

    auto cnt_le = [&](unsigned p) {
        int c = 0;
#pragma unroll
        for (int t = 0; t < 16; t++) c += __popcll(__ballot(du[t] <= p));
        return c;
    };
    auto find_T = [&](int K) {  // smallest T with cnt_le(T) >= K  (wave-uniform)
        unsigned lo = 0u, hi = 0xFFFFFFFFu;
        while (lo < hi) {
            unsigned mid = lo + ((hi - lo) >> 1);
            if (cnt_le(mid) >= K) hi = mid; else lo = mid + 1;
        }
        return hi;
    };
    auto emit = [&](int K, unsigned T, int* out) {
        int base = 0;
#pragma unroll
        for (int t = 0; t < 16; t++) {
            bool lt = du[t] < T;
            unsigned long long mk = __ballot(lt);
            if (lt) out[base + __popcll(mk & lmask)] = t * 64 + lane;
            base += __popcll(mk);
        }
        int need = K - base, eb = 0;
#pragma unroll
        for (int t = 0; t < 16; t++) {
            bool eq = du[t] == T;
            unsigned long long mk = __ballot(eq);
            if (eq) {
                int r = eb + __popcll(mk & lmask);
                if (r < need) out[base + r] = t * 64 + lane;
            }
            eb += __popcll(mk);
        }
    };
    unsigned T16 = find_T(16);
    emit(16, T16, k16 + ((size_t)b * 1024 + n) * 16);
    unsigned T64 = find_T(64);
    emit(64, T64, k64 + ((size_t)b * 1024 + n) * 64);
}

// ---------------------------------------------------------------- knn attention
// hqkv[row][768]: q at 0, k at 256, v at 512.
template <int KK>
__global__ __launch_bounds__(256) void k_attn(const float* __restrict__ hqkv, const int* __restrict__ kidx,
                                              float* __restrict__ out) {
    int bn = blockIdx.x;
    int b = bn >> 10;
    int tid = threadIdx.x;
    __shared__ float sq[256];
    __shared__ float sa[8][KK];
    __shared__ int si[KK];
    if (tid < KK) si[tid] = kidx[(size_t)bn * KK + tid];
    sq[tid] = hqkv[(size_t)bn * 768 + tid] * 0.17677669529663689f;  // DH^-0.5
    __syncthreads();
    const float* kvb = hqkv + (size_t)b * 1024 * 768;
#pragma unroll
    for (int pair = tid; pair < 8 * KK; pair += 256) {
        int s = pair & (KK - 1);
        int h = pair / KK;
        const float4* kr = (const float4*)(kvb + (size_t)si[s] * 768 + 256 + h * 32);
        const float4* q4 = (const float4*)&sq[h * 32];
        float a0 = 0.f, a1 = 0.f, a2 = 0.f, a3 = 0.f;
#pragma unroll
        for (int e = 0; e < 8; e++) {
            float4 kv = kr[e];
            float4 qv = q4[e];
            a0 = fmaf(kv.x, qv.x, a0);
            a1 = fmaf(kv.y, qv.y, a1);
            a2 = fmaf(kv.z, qv.z, a2);
            a3 = fmaf(kv.w, qv.w, a3);
        }
        sa[h][s] = (a0 + a1) + (a2 + a3);
    }
    __syncthreads();
    int h = tid >> 5, d = tid & 31;
    float mx = -1e30f;
    for (int s = d; s < KK; s += 32) mx = fmaxf(mx, sa[h][s]);
#pragma unroll
    for (int o = 16; o; o >>= 1) mx = fmaxf(mx, __shfl_xor(mx, o, 32));
    float sum = 0.0f;
    for (int s = d; s < KK; s += 32) {
        float e = __expf(sa[h][s] - mx);
        sa[h][s] = e;
        sum += e;
    }
#pragma unroll
    for (int o = 16; o; o >>= 1) sum += __shfl_xor(sum, o, 32);
    float inv = 1.0f / sum;
    __syncthreads();
    float acc = 0.0f;
    for (int s = 0; s < KK; s++) {
        float vv = kvb[(size_t)si[s] * 768 + 512 + tid];
        acc += sa[h][s] * vv;
    }
    out[(size_t)bn * 256 + tid] = acc * inv;
}

// ------------------------------------------------- ms-deform sampling (value bf16; offaw concat [648])
// Phase A: per-head softmax of aw (8 threads). Phase B: 216 threads compute the
// 4 bilinear corners per (h,l,p) -> packed (w*aw, row byte offset) in LDS.
// Phase C: thread=(par,h,d2): 54 corners x 1 dword (2 bf16 channels), LDS meta
// reads are 16-lane broadcasts; two halves reduced via LDS.
__global__ __launch_bounds__(256) void k_msdeform(const float* __restrict__ offaw, const float* __restrict__ cpos,
                                                  const unsigned short* __restrict__ value, float* __restrict__ out) {
    int bn = blockIdx.x;
    int b = bn >> 10;
    int tid = threadIdx.x;
    __shared__ float aw[216];
    __shared__ uint2 meta[864];  // [(h*27+lp)*4+c] : .x = f32 weight bits, .y = row byte offset
    __shared__ float sacc[2][256];
    if (tid < 216) aw[tid] = offaw[(size_t)bn * 648 + 432 + tid];
    __syncthreads();
    if (tid < 8) {
        float mx = -1e30f;
        for (int p = 0; p < 27; p++) mx = fmaxf(mx, aw[tid * 27 + p]);
        float s = 0.0f;
        for (int p = 0; p < 27; p++) {
            float e = __expf(aw[tid * 27 + p] - mx);
            aw[tid * 27 + p] = e;
            s += e;
        }
        float inv = 1.0f / s;
        for (int p = 0; p < 27; p++) aw[tid * 27 + p] *= inv;
    }
    __syncthreads();
    if (tid < 216) {
        int h = tid / 27, lp = tid - h * 27;
        int l = lp / 9;
        const int dims[3] = {128, 64, 32};
        const int starts[3] = {0, 16384, 20480};
        int Wl = dims[l], st = starts[l];
        float rx = cpos[(size_t)bn * 6 + l * 2], ry = cpos[(size_t)bn * 6 + l * 2 + 1];
        float ox = offaw[(size_t)bn * 648 + h * 54 + lp * 2];
        float oy = offaw[(size_t)bn * 648 + h * 54 + lp * 2 + 1];
        float rw = 1.0f / (float)Wl;
        float xf = (rx + ox * rw) * (float)Wl - 0.5f;
        float yf = (ry + oy * rw) * (float)Wl - 0.5f;
        float x0 = floorf(xf), y0 = floorf(yf);
        float wgt = aw[tid];
#pragma unroll
        for (int c = 0; c < 4; c++) {
            float ix = x0 + (float)(c & 1), iy = y0 + (float)(c >> 1);
            float w = (1.0f - fabsf(xf - ix)) * (1.0f - fabsf(yf - iy));
            bool valid = (ix >= 0.0f) & (ix <= (float)(Wl - 1)) & (iy >= 0.0f) & (iy <= (float)(Wl - 1));
            uint2 m;
            if (valid && w != 0.0f) {
                m.x = __float_as_uint(w * wgt);
                m.y = (unsigned)((st + (int)iy * Wl + (int)ix) * 512);
            } else {
                m.x = 0u;
                m.y = 0u;
            }
            meta[tid * 4 + c] = m;
        }
    }
    __syncthreads();
    int par = tid >> 7, h2 = (tid >> 4) & 7, d2 = tid & 15;
    const char* base = (const char*)(value + (size_t)b * 21504 * 256) + h2 * 64 + d2 * 4;
    const uint2* mp = &meta[h2 * 108 + par * 54];
    float a0 = 0.f, a1 = 0.f;
#pragma unroll
    for (int j = 0; j < 54; j++) {
        uint2 m = mp[j];
        unsigned v = *(const unsigned*)(base + m.y);
        float w = __uint_as_float(m.x);
        a0 = fmaf(w, __uint_as_float(v << 16), a0);
        a1 = fmaf(w, __uint_as_float(v & 0xffff0000u), a1);
    }
    int ch = h2 * 32 + d2 * 2;
    sacc[par][ch] = a0;
    sacc[par][ch + 1] = a1;
    __syncthreads();
    out[(size_t)bn * 256 + tid] = sacc[0][tid] + sacc[1][tid];
}

// ------------------------------------------- weight transpose+convert: W[K][N] f32 -> Wt[N][K] bf16
struct TJobs {
    const float* src[18];
    unsigned short* dst[18];
    int K[18];
    int N[18];
};
__global__ __launch_bounds__(256) void k_tw(TJobs j) {
    int job = blockIdx.z;
    int K = j.K[job], N = j.N[job];
    int nt = (N + 31) >> 5, kt = K >> 5;
    if ((int)blockIdx.x >= nt || (int)blockIdx.y >= kt) return;
    __shared__ float t[32][33];
    const float* W = j.src[job];
    unsigned short* Wt = j.dst[job];
    int x = threadIdx.x & 31, y = threadIdx.x >> 5;
    int n0 = blockIdx.x << 5, k0 = blockIdx.y << 5;
#pragma unroll
    for (int i = 0; i < 32; i += 8) {
        int n = n0 + x;
        t[y + i][x] = (n < N) ? W[(size_t)(k0 + y + i) * N + n] : 0.0f;
    }
    __syncthreads();
#pragma unroll
    for (int i = 0; i < 32; i += 8) {
        int n = n0 + y + i;
        if (n < N) Wt[(size_t)n * K + k0 + x] = f2bf(t[x][y + i]);
    }
}

// ---------------------------------------------------------------- bf16 MFMA GEMM
// C[M,N] = act( A'[M,K] @ W[K,N] + bias ) (+res).  W passed as Wt[N][K] bf16.
// A' = (A-mean)*rstd*g+b per row if LNA. BM=64 fixed, BK=32, 256 thr = 4 waves.
// BIAS2: bias for col>=bsplit comes from bias2[col-bsplit].
template <int BN, int WGM, int WGN, bool LNA, bool BIAS, bool BIAS2, bool GELUF, bool RES, bool OBF16>
__global__ __launch_bounds__(256) void k_mgemm(const float* __restrict__ A, const unsigned short* __restrict__ Bt,
                                               const float* __restrict__ bias, const float* __restrict__ bias2,
                                               int bsplit, const float* __restrict__ res,
                                               const float* __restrict__ stats, const float* __restrict__ lng,
                                               const float* __restrict__ lnb, void* __restrict__ Cout,
                                               int M, int K, int Ncol) {
    constexpr int BM = 64, BK = 32;
    constexpr int WAVE_M = BM / WGM, WAVE_N = BN / WGN;
    constexpr int FM = WAVE_M / 16, FN = WAVE_N / 16;
    constexpr int BUN = BN / 64;  // 16B B-units per thread
    __shared__ __align__(16) short a_lds[4][BM][8];
    __shared__ __align__(16) short b_lds[4][BN][8];
    int tid = threadIdx.x;
    int am0 = blockIdx.y * BM, bn0 = blockIdx.x * BN;
    int ar = tid >> 2, akc = tid & 3;
    const float* Arow = A + (size_t)(am0 + ar) * K + akc * 8;
    float mean = 0.0f, rstd = 0.0f;
    if (LNA) {
        mean = stats[(size_t)(am0 + ar) * 2];
        rstd = stats[(size_t)(am0 + ar) * 2 + 1];
    }
    float4 a0, a1, g0, g1, c0, c1;
    int4 bq[BUN];
    int nsteps = K / BK;

    auto load_tile = [&](int k0) {
        a0 = *(const float4*)(Arow + k0);
        a1 = *(const float4*)(Arow + k0 + 4);
        if (LNA) {
            g0 = *(const float4*)(lng + k0 + akc * 8);
            g1 = *(const float4*)(lng + k0 + akc * 8 + 4);
            c0 = *(const float4*)(lnb + k0 + akc * 8);
            c1 = *(const float4*)(lnb + k0 + akc * 8 + 4);
        }
#pragma unroll
        for (int jj = 0; jj < BUN; jj++) {
            int u = tid + 256 * jj;
            int col = u >> 2, kc = u & 3;
            int gn = bn0 + col;
            if (gn < Ncol)
                bq[jj] = *(const int4*)(Bt + (size_t)gn * K + k0 + kc * 8);
            else
                bq[jj] = make_int4(0, 0, 0, 0);
        }
    };
    auto write_lds = [&]() {
        float v[8] = {a0.x, a0.y, a0.z, a0.w, a1.x, a1.y, a1.z, a1.w};
        if (LNA) {
            float gg[8] = {g0.x, g0.y, g0.z, g0.w, g1.x, g1.y, g1.z, g1.w};
            float bb[8] = {c0.x, c0.y, c0.z, c0.w, c1.x, c1.y, c1.z, c1.w};
#pragma unroll
            for (int e = 0; e < 8; e++) v[e] = (v[e] - mean) * rstd * gg[e] + bb[e];
        }
        bf16x8 pk;
#pragma unroll
        for (int e = 0; e < 8; e++) pk[e] = (short)f2bf(v[e]);
        *(bf16x8*)(&a_lds[akc][ar][0]) = pk;
#pragma unroll
        for (int jj = 0; jj < BUN; jj++) {
            int u = tid + 256 * jj;
            int col = u >> 2, kc = u & 3;
            *(int4*)(&b_lds[kc][col][0]) = bq[jj];
        }
    };
    int lane = tid & 63, wid = tid >> 6;
    int wm = wid / WGN, wn = wid % WGN;
    int fr = lane & 15, fkc = lane >> 4;
    floatx4 acc[FM][FN] = {};

    load_tile(0);
    for (int t = 0; t < nsteps; ++t) {
        if (t) __syncthreads();
        write_lds();
        __syncthreads();
        if (t + 1 < nsteps) load_tile((t + 1) * BK);
        bf16x8 af[FM], bf[FN];
#pragma unroll
        for (int m = 0; m < FM; m++) af[m] = *(const bf16x8*)(&a_lds[fkc][wm * WAVE_M + m * 16 + fr][0]);
#pragma unroll
        for (int n = 0; n < FN; n++) bf[n] = *(const bf16x8*)(&b_lds[fkc][wn * WAVE_N + n * 16 + fr][0]);
#pragma unroll
        for (int m = 0; m < FM; m++)
#pragma unroll
            for (int n = 0; n < FN; n++)
                acc[m][n] = __builtin_amdgcn_mfma_f32_16x16x32_bf16(af[m], bf[n], acc[m][n], 0, 0, 0);
    }
    // epilogue: C/D layout col=lane&15, row=(lane>>4)*4+reg
    int r4 = lane >> 4;
#pragma unroll
    for (int m = 0; m < FM; m++) {
        int row = am0 + wm * WAVE_M + m * 16 + r4 * 4;
#pragma unroll
        for (int n = 0; n < FN; n++) {
            int col = bn0 + wn * WAVE_N + n * 16 + fr;
            if (col < Ncol) {
                float bsc = 0.0f;
                if (BIAS) bsc = (BIAS2 && col >= bsplit) ? bias2[col - bsplit] : bias[col];
#pragma unroll
                for (int r = 0; r < 4; r++) {
                    size_t off = (size_t)(row + r) * Ncol + col;
                    float v = acc[m][n][r] + bsc;
                    if (GELUF) v = gelu_f(v);
                    if (RES) v += res[off];
                    if (OBF16)
                        ((unsigned short*)Cout)[off] = f2bf(v);
                    else
                        ((float*)Cout)[off] = v;
                }
            }
        }
    }
}

// ================================================================ launch
extern "C" void kernel_launch(void* const* d_in, const int* in_sizes, int n_in, void* d_out, int out_size,
                              void* d_ws, size_t ws_size, hipStream_t stream) {
    const float* xin = (const float*)d_in[0];
    const float* src = (const float*)d_in[1];
    const float* cpos = (const float*)d_in[2];
    const float* pos3 = (const float*)d_in[3];
    const float* Wpos = (const float*)d_in[6];
    const float* bpos = (const float*)d_in[7];
    const float* ln1g = (const float*)d_in[8];
    const float* ln1b = (const float*)d_in[9];
    const float* ln2g = (const float*)d_in[10];
    const float* ln2b = (const float*)d_in[11];
    const float* ln3g = (const float*)d_in[12];
    const float* ln3b = (const float*)d_in[13];
    const float* Wq = (const float*)d_in[14];
    const float* Wkv = (const float*)d_in[15];
    const float* Wosa = (const float*)d_in[16];
    const float* bosa = (const float*)d_in[17];
    const float* Wval = (const float*)d_in[18];
    const float* bval = (const float*)d_in[19];
    const float* Woff = (const float*)d_in[20];
    const float* boff = (const float*)d_in[21];
    const float* Waw = (const float*)d_in[22];
    const float* baw = (const float*)d_in[23];
    const float* Woca = (const float*)d_in[24];
    const float* boca = (const float*)d_in[25];
    const float* W1 = (const float*)d_in[26];
    const float* b1 = (const float*)d_in[27];
    const float* W2 = (const float*)d_in[28];
    const float* b2 = (const float*)d_in[29];
    float* x = (float*)d_out;

    float* ws = (float*)d_ws;
    float* sstats = ws;                     // 86016
    float* cpe = sstats + 86016;            // 524288
    float* hbuf = cpe + 524288;             // 524288
    float* hqkv = hbuf + 524288;            // 1572864 (2048*768)
    float* attn_o = hqkv + 1572864;         // 524288
    float* qbuf = attn_o + 524288;          // 524288
    float* offaw = qbuf + 524288;           // 1327104 (2048*648)
    float* cab = offaw + 1327104;           // 524288
    float* ffmid = cab + 524288;            // 1048576
    unsigned short* value = (unsigned short*)(ffmid + 1048576);  // 11010048 shorts
    int* kidx16 = (int*)(ffmid + 1048576 + 5505024);             // 32768 ints
    int* kidx64 = kidx16 + 32768;                                // 131072 ints
    unsigned short* wt = (unsigned short*)(kidx64 + 131072);     // 1642496 shorts

    const size_t WT_STRIDE = 821248;
    // per-depth offsets: Wqkv[768][256] (q rows 0..255, kv rows 256..767), then others
    const size_t O_WQKV = 0, O_WOSA = 196608, O_WVAL = 262144, O_WOFFAW = 327680,
                 O_WOCA = 493568, O_W1 = 559104, O_W2 = 690176;

    TJobs tj;
    for (int d = 0; d < 2; d++) {
        int base = d * 9;
        unsigned short* wd = wt + (size_t)d * WT_STRIDE;
        tj.src[base + 0] = Wq + (size_t)d * 65536;    tj.dst[base + 0] = wd + O_WQKV;          tj.K[base + 0] = 256; tj.N[base + 0] = 256;
        tj.src[base + 1] = Wkv + (size_t)d * 131072;  tj.dst[base + 1] = wd + O_WQKV + 65536;  tj.K[base + 1] = 256; tj.N[base + 1] = 512;
        tj.src[base + 2] = Wosa + (size_t)d * 65536;  tj.dst[base + 2] = wd + O_WOSA;          tj.K[base + 2] = 256; tj.N[base + 2] = 256;
        tj.src[base + 3] = Wval + (size_t)d * 65536;  tj.dst[base + 3] = wd + O_WVAL;          tj.K[base + 3] = 256; tj.N[base + 3] = 256;
        tj.src[base + 4] = Woff + (size_t)d * 110592; tj.dst[base + 4] = wd + O_WOFFAW;        tj.K[base + 4] = 256; tj.N[base + 4] = 432;
        tj.src[base + 5] = Waw + (size_t)d * 55296;   tj.dst[base + 5] = wd + O_WOFFAW + 110592; tj.K[base + 5] = 256; tj.N[base + 5] = 216;
        tj.src[base + 6] = Woca + (size_t)d * 65536;  tj.dst[base + 6] = wd + O_WOCA;          tj.K[base + 6] = 256; tj.N[base + 6] = 256;
        tj.src[base + 7] = W1 + (size_t)d * 131072;   tj.dst[base + 7] = wd + O_W1;            tj.K[base + 7] = 256; tj.N[base + 7] = 512;
        tj.src[base + 8] = W2 + (size_t)d * 131072;   tj.dst[base + 8] = wd + O_W2;            tj.K[base + 8] = 512; tj.N[base + 8] = 256;
    }
    k_tw<<<dim3(16, 16, 18), 256, 0, stream>>>(tj);

    k_copy<<<512, 256, 0, stream>>>((const float4*)xin, (float4*)x, 131072);
    k_rowstats<<<10752, 256, 0, stream>>>(src, sstats);
    k_cpe<<<2048, 256, 0, stream>>>(cpos, Wpos, bpos, cpe);
    k_knn2<<<512, 256, 0, stream>>>(pos3, kidx16, kidx64);

    for (int i = 0; i < 2; i++) {
        unsigned short* wd = wt + (size_t)i * WT_STRIDE;
        // ---- self-attention (KNN) ----
        k_lnfused<<<512, 256, 0, stream>>>(x, cpe, nullptr, ln1g + i * 256, ln1b + i * 256, hbuf);
        k_mgemm<64, 2, 2, false, false, false, false, false, false><<<dim3(12, 32), 256, 0, stream>>>(
            hbuf, wd + O_WQKV, nullptr, nullptr, 0, nullptr, nullptr, nullptr, nullptr, hqkv, 2048, 256, 768);
        if (i == 0)
            k_attn<16><<<2048, 256, 0, stream>>>(hqkv, kidx16, attn_o);
        else
            k_attn<64><<<2048, 256, 0, stream>>>(hqkv, kidx64, attn_o);
        k_mgemm<64, 2, 2, false, true, false, false, true, false><<<dim3(4, 32), 256, 0, stream>>>(
            attn_o, wd + O_WOSA, bosa + i * 256, nullptr, 0, x, nullptr, nullptr, nullptr, x, 2048, 256, 256);

        // ---- ms-deform cross-attention ----
        k_lnfused<<<512, 256, 0, stream>>>(x, nullptr, cpe, ln2g + i * 256, ln2b + i * 256, qbuf);
        k_mgemm<256, 1, 4, true, true, false, false, false, true><<<dim3(1, 672), 256, 0, stream>>>(
            src, wd + O_WVAL, bval + i * 256, nullptr, 0, nullptr, sstats, ln2g + i * 256, ln2b + i * 256, value, 43008, 256, 256);
        k_mgemm<64, 2, 2, false, true, true, false, false, false><<<dim3(11, 32), 256, 0, stream>>>(
            qbuf, wd + O_WOFFAW, boff + i * 432, baw + i * 216, 432, nullptr, nullptr, nullptr, nullptr, offaw, 2048, 256, 648);
        k_msdeform<<<2048, 256, 0, stream>>>(offaw, cpos, value, cab);
        k_mgemm<64, 2, 2, false, true, false, false, true, false><<<dim3(4, 32), 256, 0, stream>>>(
            cab, wd + O_WOCA, boca + i * 256, nullptr, 0, x, nullptr, nullptr, nullptr, x, 2048, 256, 256);

        // ---- FFN ----
        k_lnfused<<<512, 256, 0, stream>>>(x, nullptr, nullptr, ln3g + i * 256, ln3b + i * 256, hbuf);
        k_mgemm<64, 2, 2, false, true, false, true, false, false><<<dim3(8, 32), 256, 0, stream>>>(
            hbuf, wd + O_W1, b1 + i * 512, nullptr, 0, nullptr, nullptr, nullptr, nullptr, ffmid, 2048, 256, 512);
        k_mgemm<64, 2, 2, false, true, false, false, true, false><<<dim3(4, 32), 256, 0, stream>>>(
            ffmid, wd + O_W2, b2 + i * 256, nullptr, 0, x, nullptr, nullptr, nullptr, x, 2048, 512, 256);
    }
}